// Round 3
// baseline (572.517 us; speedup 1.0000x reference)
//
#include <hip/hip_runtime.h>
#include <stdint.h>

typedef unsigned short u16;
typedef __attribute__((ext_vector_type(8))) short frag8;   // 8 bf16 in 4 VGPRs
typedef __attribute__((ext_vector_type(4))) float f32x4;
typedef __attribute__((ext_vector_type(4))) unsigned short u16x4;

#define MFMA_BF16(a,b,c) __builtin_amdgcn_mfma_f32_16x16x32_bf16((a),(b),(c),0,0,0)
#define SMSCALE 0.18033688011112042f  /* (1/sqrt(64)) * log2(e) */

__device__ __forceinline__ u16 f2bf(float f) {
  union { float f; uint32_t u; } c; c.f = f;
  uint32_t u = c.u;
  uint32_t r = (u + 0x7fffu + ((u >> 16) & 1u)) >> 16;
  return (u16)r;
}

// pack two floats' bf16 (round-half-up) into one u32: low=a, high=b
__device__ __forceinline__ uint32_t pack_bf16(float a, float b) {
  uint32_t au = __float_as_uint(a) + 0x8000u;
  uint32_t bu = __float_as_uint(b) + 0x8000u;
  return __builtin_amdgcn_perm(bu, au, 0x07060302u);
}

__device__ __forceinline__ void async16(const void* g, void* l) {
  __builtin_amdgcn_global_load_lds((const __attribute__((address_space(1))) void*)g,
                                   (__attribute__((address_space(3))) void*)l,
                                   16, 0, 0);
}

// ---------------- convert x (fp32 -> bf16) ----------------
__global__ __launch_bounds__(256) void k_convert_x(const float4* __restrict__ x,
                                                   u16* __restrict__ xb) {
  int i = blockIdx.x * 256 + threadIdx.x;
  float4 v = x[i];
  u16x4 o;
  o.x = f2bf(v.x); o.y = f2bf(v.y); o.z = f2bf(v.z); o.w = f2bf(v.w);
  *(u16x4*)(xb + (size_t)i * 4) = o;
}

// ---------------- transpose all 4 W (fp32 [k][n] -> bf16 [n][k]) ----------------
__global__ __launch_bounds__(256) void k_transpose_w4(
    const float* __restrict__ W0, const float* __restrict__ W1,
    const float* __restrict__ W2, const float* __restrict__ W3,
    u16* __restrict__ D0, u16* __restrict__ D1,
    u16* __restrict__ D2, u16* __restrict__ D3) {
  __shared__ float tile[64][65];
  const int z = blockIdx.z;
  const float* src = (z == 0) ? W0 : (z == 1) ? W1 : (z == 2) ? W2 : W3;
  u16* dst = (z == 0) ? D0 : (z == 1) ? D1 : (z == 2) ? D2 : D3;
  const int bx = blockIdx.x * 64;  // k base
  const int by = blockIdx.y * 64;  // n base
  const int t = threadIdx.x;
  const int tc = (t & 15) * 4;
  const int tr = t >> 4;
  #pragma unroll
  for (int p = 0; p < 4; ++p) {
    int r = tr + p * 16;
    float4 v = *(const float4*)(src + (size_t)(bx + r) * 1024 + by + tc);
    tile[r][tc + 0] = v.x; tile[r][tc + 1] = v.y;
    tile[r][tc + 2] = v.z; tile[r][tc + 3] = v.w;
  }
  __syncthreads();
  #pragma unroll
  for (int p = 0; p < 4; ++p) {
    int r = tr + p * 16;
    u16x4 o;
    o.x = f2bf(tile[tc + 0][r]);
    o.y = f2bf(tile[tc + 1][r]);
    o.z = f2bf(tile[tc + 2][r]);
    o.w = f2bf(tile[tc + 3][r]);
    *(u16x4*)(dst + (size_t)(by + r) * 1024 + bx + tc) = o;
  }
}

// ---------------- shared 128x128 GEMM core (A[M][1024] @ Bt[N][1024]^T) ----------------
__device__ __forceinline__ void gemm_core(const u16* __restrict__ A, const u16* __restrict__ Bt,
                                          u16* As, u16* Bs, int m0, int n0, f32x4 acc[4][4]) {
  const int t = threadIdx.x;
  const int lane = t & 63, wv = t >> 6;
  const int lm = lane & 15, quad = lane >> 4;
  const int wr = wv >> 1, wc = wv & 1;
  for (int k0 = 0; k0 < 1024; k0 += 32) {
    #pragma unroll
    for (int it = 0; it < 2; ++it) {
      int chunk = it * 256 + t;
      int r = chunk >> 2, c8 = (chunk & 3) * 8;
      u16* ldsA = As + (size_t)(it * 256 + wv * 64) * 8;
      u16* ldsB = Bs + (size_t)(it * 256 + wv * 64) * 8;
      async16(A  + (size_t)(m0 + r) * 1024 + k0 + c8, ldsA);
      async16(Bt + (size_t)(n0 + r) * 1024 + k0 + c8, ldsB);
    }
    __syncthreads();
    frag8 a[4], b[4];
    #pragma unroll
    for (int i = 0; i < 4; ++i) a[i] = *(const frag8*)(As + (wr * 64 + i * 16 + lm) * 32 + quad * 8);
    #pragma unroll
    for (int j = 0; j < 4; ++j) b[j] = *(const frag8*)(Bs + (wc * 64 + j * 16 + lm) * 32 + quad * 8);
    #pragma unroll
    for (int i = 0; i < 4; ++i)
      #pragma unroll
      for (int j = 0; j < 4; ++j)
        acc[i][j] = MFMA_BF16(a[i], b[j], acc[i][j]);
    __syncthreads();
  }
}

// ---------------- QKV projection GEMM (Q pre-scaled; V written transposed) ----------------
__global__ __launch_bounds__(256) void k_gemm_qkv(const u16* __restrict__ xb,
    const u16* __restrict__ Wqt, const u16* __restrict__ Wkt, const u16* __restrict__ Wvt,
    u16* __restrict__ Qg, u16* __restrict__ Kg, u16* __restrict__ Vtg) {
  __shared__ __attribute__((aligned(16))) char smem[64 * 136 * 2];  // >= As+Bs (16384)
  u16* As = (u16*)smem;
  u16* Bs = (u16*)smem + 4096;
  u16* T  = (u16*)smem;           // 64 x 136 u16, reused after gemm_core
  const int z = blockIdx.z;
  const u16* Bt = (z == 0) ? Wqt : (z == 1) ? Wkt : Wvt;
  const int m0 = blockIdx.x * 128, n0 = blockIdx.y * 128;
  f32x4 acc[4][4] = {};
  gemm_core(xb, Bt, As, Bs, m0, n0, acc);
  const int t = threadIdx.x, lane = t & 63, wv = t >> 6;
  const int lm = lane & 15, quad = lane >> 4;
  const int wr = wv >> 1, wc = wv & 1;
  if (z < 2) {
    u16* tgt = (z == 0) ? Qg : Kg;
    const float sc = (z == 0) ? SMSCALE : 1.0f;   // fold softmax scale into Q
    #pragma unroll
    for (int i = 0; i < 4; ++i)
      #pragma unroll
      for (int j = 0; j < 4; ++j) {
        const int col = n0 + wc * 64 + j * 16 + lm;
        const int h = col >> 6, d = col & 63;
        #pragma unroll
        for (int reg = 0; reg < 4; ++reg) {
          const int row = m0 + wr * 64 + i * 16 + quad * 4 + reg;
          const int bb = row >> 11, nn = row & 2047;
          tgt[(((size_t)bb * 16 + h) * 2048 + nn) * 64 + d] = f2bf(acc[i][j][reg] * sc);
        }
      }
  } else {
    // V: transpose tile through LDS, two 64-col passes -> Vtg [bh][d][n]
    const int bb = m0 >> 11, nn0 = m0 & 2047;
    const int h0 = n0 >> 6;
    #pragma unroll
    for (int p = 0; p < 2; ++p) {
      if (wc == p) {
        #pragma unroll
        for (int i = 0; i < 4; ++i)
          #pragma unroll
          for (int j = 0; j < 4; ++j) {
            const int rT = j * 16 + lm;                         // d within pass (0..63)
            #pragma unroll
            for (int reg = 0; reg < 4; ++reg) {
              const int cT = wr * 64 + i * 16 + quad * 4 + reg; // token local (0..127)
              T[rT * 136 + cT] = f2bf(acc[i][j][reg]);
            }
          }
      }
      __syncthreads();
      #pragma unroll
      for (int cc = 0; cc < 4; ++cc) {
        int chunk = cc * 256 + t;
        int r = chunk >> 4, tk = (chunk & 15) * 8;
        frag8 v = *(const frag8*)(T + r * 136 + tk);
        *(frag8*)(Vtg + (((size_t)bb * 16 + h0 + p) * 64 + r) * 2048 + nn0 + tk) = v;
      }
      __syncthreads();
    }
  }
}

// ---------------- flash attention (causal), joint-pair K/V staging, no running max ----------------
__device__ __forceinline__ void attn_tile(const u16* Ks, const u16* Vts, u16* PsW,
                                          const frag8 aq[2], f32x4 o[4], float& l_run,
                                          int lm, int quad, int wv, bool diag) {
  f32x4 s[4];
  #pragma unroll
  for (int kt = 0; kt < 4; ++kt) {
    f32x4 z = {0.f, 0.f, 0.f, 0.f};
    #pragma unroll
    for (int dd = 0; dd < 2; ++dd) {
      frag8 ak = *(const frag8*)(Ks + (kt * 16 + lm) * 64 + (((dd * 4 + quad) ^ (lm & 7)) * 8));
      z = MFMA_BF16(ak, aq[dd], z);
    }
    s[kt] = z;
  }
  if (diag) {  // diagonal tile mask (wave-uniform branch); key>q -> -inf
    #pragma unroll
    for (int kt = 0; kt < 4; ++kt)
      #pragma unroll
      for (int rg = 0; rg < 4; ++rg)
        if (kt * 16 + quad * 4 + rg > wv * 16 + lm) s[kt][rg] = -3.0e38f;
  }
  float rs = 0.f;
  #pragma unroll
  for (int kt = 0; kt < 4; ++kt) {
    float p0 = exp2f(s[kt][0]);   // Q was pre-scaled by 1/sqrt(d)*log2(e)
    float p1 = exp2f(s[kt][1]);
    float p2 = exp2f(s[kt][2]);
    float p3 = exp2f(s[kt][3]);
    rs += (p0 + p1) + (p2 + p3);
    *(uint32_t*)(PsW + lm * 72 + kt * 16 + quad * 4)     = pack_bf16(p0, p1);
    *(uint32_t*)(PsW + lm * 72 + kt * 16 + quad * 4 + 2) = pack_bf16(p2, p3);
  }
  l_run += rs;   // cross-quad reduction deferred to epilogue
  #pragma unroll
  for (int ks = 0; ks < 2; ++ks) {
    frag8 bp = *(const frag8*)(PsW + lm * 72 + ks * 32 + quad * 8);
    #pragma unroll
    for (int dt = 0; dt < 4; ++dt) {
      frag8 av = *(const frag8*)(Vts + (dt * 16 + lm) * 64 + (((ks * 4 + quad) ^ (lm & 7)) * 8));
      o[dt] = MFMA_BF16(av, bp, o[dt]);
    }
  }
}

__global__ __launch_bounds__(256, 5) void k_attn(const u16* __restrict__ Qg,
                                                 const u16* __restrict__ Kg,
                                                 const u16* __restrict__ Vtg,
                                                 u16* __restrict__ ctx) {
  __shared__ __attribute__((aligned(16))) u16 Ks[64 * 64];    // swizzled
  __shared__ __attribute__((aligned(16))) u16 Vts[64 * 64];   // [d][key], swizzled
  __shared__ __attribute__((aligned(16))) u16 Ps[4 * 16 * 72];
  // swizzled grid: bid = pair*64 + bh_hi*8 + bh_lo  ->  bid%8 == bh%8 (XCD-stable per bh)
  const int bid = blockIdx.x;
  const int pair = bid >> 6;
  const int bh = ((bid >> 3) & 7) * 8 + (bid & 7);
  const int qt_lo = pair, qt_hi = 31 - pair;
  const int t = threadIdx.x, lane = t & 63, wv = t >> 6;
  const int lm = lane & 15, quad = lane >> 4;
  const int b = bh >> 4, h = bh & 15;
  u16* const PsW = Ps + wv * (16 * 72);

  frag8 aq_lo[2], aq_hi[2];
  {
    const u16* ql = Qg + ((size_t)bh * 2048 + qt_lo * 64 + wv * 16 + lm) * 64 + quad * 8;
    const u16* qh = Qg + ((size_t)bh * 2048 + qt_hi * 64 + wv * 16 + lm) * 64 + quad * 8;
    aq_lo[0] = *(const frag8*)(ql);  aq_lo[1] = *(const frag8*)(ql + 32);
    aq_hi[0] = *(const frag8*)(qh);  aq_hi[1] = *(const frag8*)(qh + 32);
  }
  float l_lo = 0.f, l_hi = 0.f;
  f32x4 o_lo[4] = {}, o_hi[4] = {};

  for (int kt0 = 0; kt0 <= qt_hi; ++kt0) {
    #pragma unroll
    for (int it = 0; it < 2; ++it) {
      int chunk = it * 256 + t;
      int r = chunk >> 3, c = chunk & 7;
      int sc = (c ^ (r & 7)) * 8;
      async16(Kg  + ((size_t)bh * 2048 + kt0 * 64 + r) * 64 + sc, Ks  + (size_t)(it * 256 + wv * 64) * 8);
      async16(Vtg + ((size_t)bh * 64 + r) * 2048 + kt0 * 64 + sc, Vts + (size_t)(it * 256 + wv * 64) * 8);
    }
    __syncthreads();
    attn_tile(Ks, Vts, PsW, aq_hi, o_hi, l_hi, lm, quad, wv, kt0 == qt_hi);
    if (kt0 <= qt_lo)
      attn_tile(Ks, Vts, PsW, aq_lo, o_lo, l_lo, lm, quad, wv, kt0 == qt_lo);
    __syncthreads();
  }

  // epilogues: reduce l across quads, normalize, transpose O^T->[q][d] via PsW, 16B stores
  #pragma unroll
  for (int e = 0; e < 2; ++e) {
    const int qt = e ? qt_lo : qt_hi;
    f32x4* o = e ? o_lo : o_hi;
    float l = e ? l_lo : l_hi;
    l += __shfl_xor(l, 16);
    l += __shfl_xor(l, 32);
    const float inv = 1.0f / l;
    #pragma unroll
    for (int dt = 0; dt < 4; ++dt) {
      *(uint32_t*)(PsW + lm * 72 + dt * 16 + quad * 4)     = pack_bf16(o[dt][0] * inv, o[dt][1] * inv);
      *(uint32_t*)(PsW + lm * 72 + dt * 16 + quad * 4 + 2) = pack_bf16(o[dt][2] * inv, o[dt][3] * inv);
    }
    const int rr = lane >> 2, cc = (lane & 3) * 8;
    const size_t row = (size_t)b * 2048 + qt * 64 + wv * 16 + rr;
    #pragma unroll
    for (int half = 0; half < 2; ++half) {
      frag8 vo = *(const frag8*)(PsW + rr * 72 + cc + half * 32);
      *(frag8*)(ctx + row * 1024 + h * 64 + cc + half * 32) = vo;
    }
  }
}

// ---------------- output projection GEMM (+bias, fp32 out) ----------------
__global__ __launch_bounds__(256) void k_gemm_out(const u16* __restrict__ ctx,
    const u16* __restrict__ Wot, const float* __restrict__ bo, float* __restrict__ out) {
  __shared__ __attribute__((aligned(16))) u16 As[128 * 32];
  __shared__ __attribute__((aligned(16))) u16 Bs[128 * 32];
  const int m0 = blockIdx.x * 128, n0 = blockIdx.y * 128;
  f32x4 acc[4][4] = {};
  gemm_core(ctx, Wot, As, Bs, m0, n0, acc);
  const int t = threadIdx.x, lane = t & 63, wv = t >> 6;
  const int lm = lane & 15, quad = lane >> 4;
  const int wr = wv >> 1, wc = wv & 1;
  #pragma unroll
  for (int i = 0; i < 4; ++i)
    #pragma unroll
    for (int j = 0; j < 4; ++j) {
      const int col = n0 + wc * 64 + j * 16 + lm;
      const float bias = bo[col];
      #pragma unroll
      for (int reg = 0; reg < 4; ++reg) {
        const int row = m0 + wr * 64 + i * 16 + quad * 4 + reg;
        out[(size_t)row * 1024 + col] = acc[i][j][reg] + bias;
      }
    }
}

extern "C" void kernel_launch(void* const* d_in, const int* in_sizes, int n_in,
                              void* d_out, int out_size, void* d_ws, size_t ws_size,
                              hipStream_t stream) {
  const float* x  = (const float*)d_in[0];
  const float* Wq = (const float*)d_in[1];
  const float* Wk = (const float*)d_in[2];
  const float* Wv = (const float*)d_in[3];
  const float* Wo = (const float*)d_in[4];
  const float* bo = (const float*)d_in[5];
  float* out = (float*)d_out;
  char* ws = (char*)d_ws;

  u16* xb   = (u16*)(ws);                          // 16 MB
  u16* Wqt  = (u16*)(ws + ((size_t)16 << 20));     //  2 MB each
  u16* Wkt  = (u16*)(ws + ((size_t)18 << 20));
  u16* Wvt  = (u16*)(ws + ((size_t)20 << 20));
  u16* Wot  = (u16*)(ws + ((size_t)22 << 20));
  u16* Qg   = (u16*)(ws + ((size_t)24 << 20));     // 16 MB [b,h,n,64] (pre-scaled)
  u16* Kg   = (u16*)(ws + ((size_t)40 << 20));     // 16 MB [b,h,n,64]
  u16* Vtg  = (u16*)(ws + ((size_t)56 << 20));     // 16 MB [b,h,64,n]
  u16* ctxb = (u16*)(ws + ((size_t)72 << 20));     // 16 MB

  k_convert_x<<<8192, 256, 0, stream>>>((const float4*)x, xb);
  k_transpose_w4<<<dim3(16, 16, 4), 256, 0, stream>>>(Wq, Wk, Wv, Wo, Wqt, Wkt, Wvt, Wot);
  k_gemm_qkv<<<dim3(64, 8, 3), 256, 0, stream>>>(xb, Wqt, Wkt, Wvt, Qg, Kg, Vtg);
  k_attn<<<1024, 256, 0, stream>>>(Qg, Kg, Vtg, ctxb);
  k_gemm_out<<<dim3(64, 8), 256, 0, stream>>>(ctxb, Wot, bo, out);
}

// Round 4
// 362.648 us; speedup vs baseline: 1.5787x; 1.5787x over previous
//
#include <hip/hip_runtime.h>
#include <stdint.h>

typedef unsigned short u16;
typedef __attribute__((ext_vector_type(8))) short frag8;   // 8 bf16 in 4 VGPRs
typedef __attribute__((ext_vector_type(4))) float f32x4;
typedef __attribute__((ext_vector_type(4))) unsigned short u16x4;

#define MFMA_BF16(a,b,c) __builtin_amdgcn_mfma_f32_16x16x32_bf16((a),(b),(c),0,0,0)
#define SMSCALE 0.18033688011112042f  /* (1/sqrt(64)) * log2(e) */

__device__ __forceinline__ u16 f2bf(float f) {
  union { float f; uint32_t u; } c; c.f = f;
  uint32_t u = c.u;
  uint32_t r = (u + 0x7fffu + ((u >> 16) & 1u)) >> 16;
  return (u16)r;
}

// pack two floats' bf16 (round-half-up) into one u32: low=a, high=b
__device__ __forceinline__ uint32_t pack_bf16(float a, float b) {
  uint32_t au = __float_as_uint(a) + 0x8000u;
  uint32_t bu = __float_as_uint(b) + 0x8000u;
  return __builtin_amdgcn_perm(bu, au, 0x07060302u);
}

__device__ __forceinline__ void async16(const void* g, void* l) {
  __builtin_amdgcn_global_load_lds((const __attribute__((address_space(1))) void*)g,
                                   (__attribute__((address_space(3))) void*)l,
                                   16, 0, 0);
}

// ---------------- convert x (fp32 -> bf16) ----------------
__global__ __launch_bounds__(256) void k_convert_x(const float4* __restrict__ x,
                                                   u16* __restrict__ xb) {
  int i = blockIdx.x * 256 + threadIdx.x;
  float4 v = x[i];
  u16x4 o;
  o.x = f2bf(v.x); o.y = f2bf(v.y); o.z = f2bf(v.z); o.w = f2bf(v.w);
  *(u16x4*)(xb + (size_t)i * 4) = o;
}

// ---------------- transpose all 4 W (fp32 [k][n] -> bf16 [n][k]) ----------------
__global__ __launch_bounds__(256) void k_transpose_w4(
    const float* __restrict__ W0, const float* __restrict__ W1,
    const float* __restrict__ W2, const float* __restrict__ W3,
    u16* __restrict__ D0, u16* __restrict__ D1,
    u16* __restrict__ D2, u16* __restrict__ D3) {
  __shared__ float tile[64][65];
  const int z = blockIdx.z;
  const float* src = (z == 0) ? W0 : (z == 1) ? W1 : (z == 2) ? W2 : W3;
  u16* dst = (z == 0) ? D0 : (z == 1) ? D1 : (z == 2) ? D2 : D3;
  const int bx = blockIdx.x * 64;  // k base
  const int by = blockIdx.y * 64;  // n base
  const int t = threadIdx.x;
  const int tc = (t & 15) * 4;
  const int tr = t >> 4;
  #pragma unroll
  for (int p = 0; p < 4; ++p) {
    int r = tr + p * 16;
    float4 v = *(const float4*)(src + (size_t)(bx + r) * 1024 + by + tc);
    tile[r][tc + 0] = v.x; tile[r][tc + 1] = v.y;
    tile[r][tc + 2] = v.z; tile[r][tc + 3] = v.w;
  }
  __syncthreads();
  #pragma unroll
  for (int p = 0; p < 4; ++p) {
    int r = tr + p * 16;
    u16x4 o;
    o.x = f2bf(tile[tc + 0][r]);
    o.y = f2bf(tile[tc + 1][r]);
    o.z = f2bf(tile[tc + 2][r]);
    o.w = f2bf(tile[tc + 3][r]);
    *(u16x4*)(dst + (size_t)(by + r) * 1024 + bx + tc) = o;
  }
}

// ---------------- shared 128x128 GEMM core (A[M][1024] @ Bt[N][1024]^T) ----------------
__device__ __forceinline__ void gemm_core(const u16* __restrict__ A, const u16* __restrict__ Bt,
                                          u16* As, u16* Bs, int m0, int n0, f32x4 acc[4][4]) {
  const int t = threadIdx.x;
  const int lane = t & 63, wv = t >> 6;
  const int lm = lane & 15, quad = lane >> 4;
  const int wr = wv >> 1, wc = wv & 1;
  for (int k0 = 0; k0 < 1024; k0 += 32) {
    #pragma unroll
    for (int it = 0; it < 2; ++it) {
      int chunk = it * 256 + t;
      int r = chunk >> 2, c8 = (chunk & 3) * 8;
      u16* ldsA = As + (size_t)(it * 256 + wv * 64) * 8;
      u16* ldsB = Bs + (size_t)(it * 256 + wv * 64) * 8;
      async16(A  + (size_t)(m0 + r) * 1024 + k0 + c8, ldsA);
      async16(Bt + (size_t)(n0 + r) * 1024 + k0 + c8, ldsB);
    }
    __syncthreads();
    frag8 a[4], b[4];
    #pragma unroll
    for (int i = 0; i < 4; ++i) a[i] = *(const frag8*)(As + (wr * 64 + i * 16 + lm) * 32 + quad * 8);
    #pragma unroll
    for (int j = 0; j < 4; ++j) b[j] = *(const frag8*)(Bs + (wc * 64 + j * 16 + lm) * 32 + quad * 8);
    #pragma unroll
    for (int i = 0; i < 4; ++i)
      #pragma unroll
      for (int j = 0; j < 4; ++j)
        acc[i][j] = MFMA_BF16(a[i], b[j], acc[i][j]);
    __syncthreads();
  }
}

// ---------------- QKV projection GEMM (Q pre-scaled; V written transposed) ----------------
__global__ __launch_bounds__(256) void k_gemm_qkv(const u16* __restrict__ xb,
    const u16* __restrict__ Wqt, const u16* __restrict__ Wkt, const u16* __restrict__ Wvt,
    u16* __restrict__ Qg, u16* __restrict__ Kg, u16* __restrict__ Vtg) {
  __shared__ __attribute__((aligned(16))) char smem[64 * 136 * 2];  // >= As+Bs (16384)
  u16* As = (u16*)smem;
  u16* Bs = (u16*)smem + 4096;
  u16* T  = (u16*)smem;           // 64 x 136 u16, reused after gemm_core
  const int z = blockIdx.z;
  const u16* Bt = (z == 0) ? Wqt : (z == 1) ? Wkt : Wvt;
  const int m0 = blockIdx.x * 128, n0 = blockIdx.y * 128;
  f32x4 acc[4][4] = {};
  gemm_core(xb, Bt, As, Bs, m0, n0, acc);
  const int t = threadIdx.x, lane = t & 63, wv = t >> 6;
  const int lm = lane & 15, quad = lane >> 4;
  const int wr = wv >> 1, wc = wv & 1;
  if (z < 2) {
    u16* tgt = (z == 0) ? Qg : Kg;
    const float sc = (z == 0) ? SMSCALE : 1.0f;   // fold softmax scale into Q
    #pragma unroll
    for (int i = 0; i < 4; ++i)
      #pragma unroll
      for (int j = 0; j < 4; ++j) {
        const int col = n0 + wc * 64 + j * 16 + lm;
        const int h = col >> 6, d = col & 63;
        #pragma unroll
        for (int reg = 0; reg < 4; ++reg) {
          const int row = m0 + wr * 64 + i * 16 + quad * 4 + reg;
          const int bb = row >> 11, nn = row & 2047;
          tgt[(((size_t)bb * 16 + h) * 2048 + nn) * 64 + d] = f2bf(acc[i][j][reg] * sc);
        }
      }
  } else {
    // V: transpose tile through LDS, two 64-col passes -> Vtg [bh][d][n]
    const int bb = m0 >> 11, nn0 = m0 & 2047;
    const int h0 = n0 >> 6;
    #pragma unroll
    for (int p = 0; p < 2; ++p) {
      if (wc == p) {
        #pragma unroll
        for (int i = 0; i < 4; ++i)
          #pragma unroll
          for (int j = 0; j < 4; ++j) {
            const int rT = j * 16 + lm;                         // d within pass (0..63)
            #pragma unroll
            for (int reg = 0; reg < 4; ++reg) {
              const int cT = wr * 64 + i * 16 + quad * 4 + reg; // token local (0..127)
              T[rT * 136 + cT] = f2bf(acc[i][j][reg]);
            }
          }
      }
      __syncthreads();
      #pragma unroll
      for (int cc = 0; cc < 4; ++cc) {
        int chunk = cc * 256 + t;
        int r = chunk >> 4, tk = (chunk & 15) * 8;
        frag8 v = *(const frag8*)(T + r * 136 + tk);
        *(frag8*)(Vtg + (((size_t)bb * 16 + h0 + p) * 64 + r) * 2048 + nn0 + tk) = v;
      }
      __syncthreads();
    }
  }
}

// ---------------- flash attention (causal), joint-pair K/V staging, no running max ----------------
__device__ __forceinline__ void attn_tile(const u16* Ks, const u16* Vts, u16* PsW,
                                          const frag8 aq[2], f32x4 o[4], float& l_run,
                                          int lm, int quad, int wv, bool diag) {
  f32x4 s[4];
  #pragma unroll
  for (int kt = 0; kt < 4; ++kt) {
    f32x4 z = {0.f, 0.f, 0.f, 0.f};
    #pragma unroll
    for (int dd = 0; dd < 2; ++dd) {
      frag8 ak = *(const frag8*)(Ks + (kt * 16 + lm) * 64 + (((dd * 4 + quad) ^ (lm & 7)) * 8));
      z = MFMA_BF16(ak, aq[dd], z);
    }
    s[kt] = z;
  }
  if (diag) {  // diagonal tile mask (wave-uniform branch); key>q -> -inf
    #pragma unroll
    for (int kt = 0; kt < 4; ++kt)
      #pragma unroll
      for (int rg = 0; rg < 4; ++rg)
        if (kt * 16 + quad * 4 + rg > wv * 16 + lm) s[kt][rg] = -3.0e38f;
  }
  float rs = 0.f;
  #pragma unroll
  for (int kt = 0; kt < 4; ++kt) {
    float p0 = exp2f(s[kt][0]);   // Q was pre-scaled by 1/sqrt(d)*log2(e)
    float p1 = exp2f(s[kt][1]);
    float p2 = exp2f(s[kt][2]);
    float p3 = exp2f(s[kt][3]);
    rs += (p0 + p1) + (p2 + p3);
    *(uint32_t*)(PsW + lm * 72 + kt * 16 + quad * 4)     = pack_bf16(p0, p1);
    *(uint32_t*)(PsW + lm * 72 + kt * 16 + quad * 4 + 2) = pack_bf16(p2, p3);
  }
  l_run += rs;   // cross-quad reduction deferred to epilogue
  #pragma unroll
  for (int ks = 0; ks < 2; ++ks) {
    frag8 bp = *(const frag8*)(PsW + lm * 72 + ks * 32 + quad * 8);
    #pragma unroll
    for (int dt = 0; dt < 4; ++dt) {
      frag8 av = *(const frag8*)(Vts + (dt * 16 + lm) * 64 + (((ks * 4 + quad) ^ (lm & 7)) * 8));
      o[dt] = MFMA_BF16(av, bp, o[dt]);
    }
  }
}

// launch_bounds(256,4): 128 unified VGPR/wave budget. (256,5) forced <=96 and the
// compiler SPILLED the doubled joint-pair accumulators to scratch -> 894 MB of
// scratch writes per dispatch (R3 counters). Do not raise the wave floor again.
__global__ __launch_bounds__(256, 4) void k_attn(const u16* __restrict__ Qg,
                                                 const u16* __restrict__ Kg,
                                                 const u16* __restrict__ Vtg,
                                                 u16* __restrict__ ctx) {
  __shared__ __attribute__((aligned(16))) u16 Ks[64 * 64];    // swizzled
  __shared__ __attribute__((aligned(16))) u16 Vts[64 * 64];   // [d][key], swizzled
  __shared__ __attribute__((aligned(16))) u16 Ps[4 * 16 * 72];
  // swizzled grid: bid = pair*64 + bh_hi*8 + bh_lo  ->  bid%8 == bh%8 (XCD-stable per bh)
  const int bid = blockIdx.x;
  const int pair = bid >> 6;
  const int bh = ((bid >> 3) & 7) * 8 + (bid & 7);
  const int qt_lo = pair, qt_hi = 31 - pair;
  const int t = threadIdx.x, lane = t & 63, wv = t >> 6;
  const int lm = lane & 15, quad = lane >> 4;
  const int b = bh >> 4, h = bh & 15;
  u16* const PsW = Ps + wv * (16 * 72);

  frag8 aq_lo[2], aq_hi[2];
  {
    const u16* ql = Qg + ((size_t)bh * 2048 + qt_lo * 64 + wv * 16 + lm) * 64 + quad * 8;
    const u16* qh = Qg + ((size_t)bh * 2048 + qt_hi * 64 + wv * 16 + lm) * 64 + quad * 8;
    aq_lo[0] = *(const frag8*)(ql);  aq_lo[1] = *(const frag8*)(ql + 32);
    aq_hi[0] = *(const frag8*)(qh);  aq_hi[1] = *(const frag8*)(qh + 32);
  }
  float l_lo = 0.f, l_hi = 0.f;
  f32x4 o_lo[4] = {}, o_hi[4] = {};

  for (int kt0 = 0; kt0 <= qt_hi; ++kt0) {
    #pragma unroll
    for (int it = 0; it < 2; ++it) {
      int chunk = it * 256 + t;
      int r = chunk >> 3, c = chunk & 7;
      int sc = (c ^ (r & 7)) * 8;
      async16(Kg  + ((size_t)bh * 2048 + kt0 * 64 + r) * 64 + sc, Ks  + (size_t)(it * 256 + wv * 64) * 8);
      async16(Vtg + ((size_t)bh * 64 + r) * 2048 + kt0 * 64 + sc, Vts + (size_t)(it * 256 + wv * 64) * 8);
    }
    __syncthreads();
    attn_tile(Ks, Vts, PsW, aq_hi, o_hi, l_hi, lm, quad, wv, kt0 == qt_hi);
    if (kt0 <= qt_lo)
      attn_tile(Ks, Vts, PsW, aq_lo, o_lo, l_lo, lm, quad, wv, kt0 == qt_lo);
    __syncthreads();
  }

  // epilogues: reduce l across quads, normalize, transpose O^T->[q][d] via PsW, 16B stores
  #pragma unroll
  for (int e = 0; e < 2; ++e) {
    const int qt = e ? qt_lo : qt_hi;
    f32x4* o = e ? o_lo : o_hi;
    float l = e ? l_lo : l_hi;
    l += __shfl_xor(l, 16);
    l += __shfl_xor(l, 32);
    const float inv = 1.0f / l;
    #pragma unroll
    for (int dt = 0; dt < 4; ++dt) {
      *(uint32_t*)(PsW + lm * 72 + dt * 16 + quad * 4)     = pack_bf16(o[dt][0] * inv, o[dt][1] * inv);
      *(uint32_t*)(PsW + lm * 72 + dt * 16 + quad * 4 + 2) = pack_bf16(o[dt][2] * inv, o[dt][3] * inv);
    }
    const int rr = lane >> 2, cc = (lane & 3) * 8;
    const size_t row = (size_t)b * 2048 + qt * 64 + wv * 16 + rr;
    #pragma unroll
    for (int half = 0; half < 2; ++half) {
      frag8 vo = *(const frag8*)(PsW + rr * 72 + cc + half * 32);
      *(frag8*)(ctx + row * 1024 + h * 64 + cc + half * 32) = vo;
    }
  }
}

// ---------------- output projection GEMM (+bias, fp32 out) ----------------
__global__ __launch_bounds__(256) void k_gemm_out(const u16* __restrict__ ctx,
    const u16* __restrict__ Wot, const float* __restrict__ bo, float* __restrict__ out) {
  __shared__ __attribute__((aligned(16))) u16 As[128 * 32];
  __shared__ __attribute__((aligned(16))) u16 Bs[128 * 32];
  const int m0 = blockIdx.x * 128, n0 = blockIdx.y * 128;
  f32x4 acc[4][4] = {};
  gemm_core(ctx, Wot, As, Bs, m0, n0, acc);
  const int t = threadIdx.x, lane = t & 63, wv = t >> 6;
  const int lm = lane & 15, quad = lane >> 4;
  const int wr = wv >> 1, wc = wv & 1;
  #pragma unroll
  for (int i = 0; i < 4; ++i)
    #pragma unroll
    for (int j = 0; j < 4; ++j) {
      const int col = n0 + wc * 64 + j * 16 + lm;
      const float bias = bo[col];
      #pragma unroll
      for (int reg = 0; reg < 4; ++reg) {
        const int row = m0 + wr * 64 + i * 16 + quad * 4 + reg;
        out[(size_t)row * 1024 + col] = acc[i][j][reg] + bias;
      }
    }
}

extern "C" void kernel_launch(void* const* d_in, const int* in_sizes, int n_in,
                              void* d_out, int out_size, void* d_ws, size_t ws_size,
                              hipStream_t stream) {
  const float* x  = (const float*)d_in[0];
  const float* Wq = (const float*)d_in[1];
  const float* Wk = (const float*)d_in[2];
  const float* Wv = (const float*)d_in[3];
  const float* Wo = (const float*)d_in[4];
  const float* bo = (const float*)d_in[5];
  float* out = (float*)d_out;
  char* ws = (char*)d_ws;

  u16* xb   = (u16*)(ws);                          // 16 MB
  u16* Wqt  = (u16*)(ws + ((size_t)16 << 20));     //  2 MB each
  u16* Wkt  = (u16*)(ws + ((size_t)18 << 20));
  u16* Wvt  = (u16*)(ws + ((size_t)20 << 20));
  u16* Wot  = (u16*)(ws + ((size_t)22 << 20));
  u16* Qg   = (u16*)(ws + ((size_t)24 << 20));     // 16 MB [b,h,n,64] (pre-scaled)
  u16* Kg   = (u16*)(ws + ((size_t)40 << 20));     // 16 MB [b,h,n,64]
  u16* Vtg  = (u16*)(ws + ((size_t)56 << 20));     // 16 MB [b,h,64,n]
  u16* ctxb = (u16*)(ws + ((size_t)72 << 20));     // 16 MB

  k_convert_x<<<8192, 256, 0, stream>>>((const float4*)x, xb);
  k_transpose_w4<<<dim3(16, 16, 4), 256, 0, stream>>>(Wq, Wk, Wv, Wo, Wqt, Wkt, Wvt, Wot);
  k_gemm_qkv<<<dim3(64, 8, 3), 256, 0, stream>>>(xb, Wqt, Wkt, Wvt, Qg, Kg, Vtg);
  k_attn<<<1024, 256, 0, stream>>>(Qg, Kg, Vtg, ctxb);
  k_gemm_out<<<dim3(64, 8), 256, 0, stream>>>(ctxb, Wot, bo, out);
}

// Round 5
// 307.221 us; speedup vs baseline: 1.8635x; 1.1804x over previous
//
#include <hip/hip_runtime.h>
#include <stdint.h>

typedef unsigned short u16;
typedef __attribute__((ext_vector_type(8))) short frag8;   // 8 bf16 in 4 VGPRs
typedef __attribute__((ext_vector_type(4))) float f32x4;
typedef __attribute__((ext_vector_type(4))) unsigned short u16x4;

#define MFMA_BF16(a,b,c) __builtin_amdgcn_mfma_f32_16x16x32_bf16((a),(b),(c),0,0,0)
#define SMSCALE 0.18033688011112042f  /* (1/sqrt(64)) * log2(e) */

__device__ __forceinline__ u16 f2bf(float f) {
  union { float f; uint32_t u; } c; c.f = f;
  uint32_t u = c.u;
  uint32_t r = (u + 0x7fffu + ((u >> 16) & 1u)) >> 16;
  return (u16)r;
}

// pack two floats' bf16 (round-half-up) into one u32: low=a, high=b
__device__ __forceinline__ uint32_t pack_bf16(float a, float b) {
  uint32_t au = __float_as_uint(a) + 0x8000u;
  uint32_t bu = __float_as_uint(b) + 0x8000u;
  return __builtin_amdgcn_perm(bu, au, 0x07060302u);
}

__device__ __forceinline__ void async16(const void* g, void* l) {
  __builtin_amdgcn_global_load_lds((const __attribute__((address_space(1))) void*)g,
                                   (__attribute__((address_space(3))) void*)l,
                                   16, 0, 0);
}

// ---------------- convert x (fp32 -> bf16) ----------------
__global__ __launch_bounds__(256) void k_convert_x(const float4* __restrict__ x,
                                                   u16* __restrict__ xb) {
  int i = blockIdx.x * 256 + threadIdx.x;
  float4 v = x[i];
  u16x4 o;
  o.x = f2bf(v.x); o.y = f2bf(v.y); o.z = f2bf(v.z); o.w = f2bf(v.w);
  *(u16x4*)(xb + (size_t)i * 4) = o;
}

// ---------------- transpose all 4 W (fp32 [k][n] -> bf16 [n][k]) ----------------
__global__ __launch_bounds__(256) void k_transpose_w4(
    const float* __restrict__ W0, const float* __restrict__ W1,
    const float* __restrict__ W2, const float* __restrict__ W3,
    u16* __restrict__ D0, u16* __restrict__ D1,
    u16* __restrict__ D2, u16* __restrict__ D3) {
  __shared__ float tile[64][65];
  const int z = blockIdx.z;
  const float* src = (z == 0) ? W0 : (z == 1) ? W1 : (z == 2) ? W2 : W3;
  u16* dst = (z == 0) ? D0 : (z == 1) ? D1 : (z == 2) ? D2 : D3;
  const int bx = blockIdx.x * 64;  // k base
  const int by = blockIdx.y * 64;  // n base
  const int t = threadIdx.x;
  const int tc = (t & 15) * 4;
  const int tr = t >> 4;
  #pragma unroll
  for (int p = 0; p < 4; ++p) {
    int r = tr + p * 16;
    float4 v = *(const float4*)(src + (size_t)(bx + r) * 1024 + by + tc);
    tile[r][tc + 0] = v.x; tile[r][tc + 1] = v.y;
    tile[r][tc + 2] = v.z; tile[r][tc + 3] = v.w;
  }
  __syncthreads();
  #pragma unroll
  for (int p = 0; p < 4; ++p) {
    int r = tr + p * 16;
    u16x4 o;
    o.x = f2bf(tile[tc + 0][r]);
    o.y = f2bf(tile[tc + 1][r]);
    o.z = f2bf(tile[tc + 2][r]);
    o.w = f2bf(tile[tc + 3][r]);
    *(u16x4*)(dst + (size_t)(by + r) * 1024 + bx + tc) = o;
  }
}

// ---------------- shared 128x128 GEMM core (A[M][1024] @ Bt[N][1024]^T) ----------------
__device__ __forceinline__ void gemm_core(const u16* __restrict__ A, const u16* __restrict__ Bt,
                                          u16* As, u16* Bs, int m0, int n0, f32x4 acc[4][4]) {
  const int t = threadIdx.x;
  const int lane = t & 63, wv = t >> 6;
  const int lm = lane & 15, quad = lane >> 4;
  const int wr = wv >> 1, wc = wv & 1;
  for (int k0 = 0; k0 < 1024; k0 += 32) {
    #pragma unroll
    for (int it = 0; it < 2; ++it) {
      int chunk = it * 256 + t;
      int r = chunk >> 2, c8 = (chunk & 3) * 8;
      u16* ldsA = As + (size_t)(it * 256 + wv * 64) * 8;
      u16* ldsB = Bs + (size_t)(it * 256 + wv * 64) * 8;
      async16(A  + (size_t)(m0 + r) * 1024 + k0 + c8, ldsA);
      async16(Bt + (size_t)(n0 + r) * 1024 + k0 + c8, ldsB);
    }
    __syncthreads();
    frag8 a[4], b[4];
    #pragma unroll
    for (int i = 0; i < 4; ++i) a[i] = *(const frag8*)(As + (wr * 64 + i * 16 + lm) * 32 + quad * 8);
    #pragma unroll
    for (int j = 0; j < 4; ++j) b[j] = *(const frag8*)(Bs + (wc * 64 + j * 16 + lm) * 32 + quad * 8);
    #pragma unroll
    for (int i = 0; i < 4; ++i)
      #pragma unroll
      for (int j = 0; j < 4; ++j)
        acc[i][j] = MFMA_BF16(a[i], b[j], acc[i][j]);
    __syncthreads();
  }
}

// ---------------- QKV projection GEMM (Q pre-scaled; V written transposed) ----------------
__global__ __launch_bounds__(256) void k_gemm_qkv(const u16* __restrict__ xb,
    const u16* __restrict__ Wqt, const u16* __restrict__ Wkt, const u16* __restrict__ Wvt,
    u16* __restrict__ Qg, u16* __restrict__ Kg, u16* __restrict__ Vtg) {
  __shared__ __attribute__((aligned(16))) char smem[64 * 136 * 2];  // >= As+Bs (16384)
  u16* As = (u16*)smem;
  u16* Bs = (u16*)smem + 4096;
  u16* T  = (u16*)smem;           // 64 x 136 u16, reused after gemm_core
  const int z = blockIdx.z;
  const u16* Bt = (z == 0) ? Wqt : (z == 1) ? Wkt : Wvt;
  const int m0 = blockIdx.x * 128, n0 = blockIdx.y * 128;
  f32x4 acc[4][4] = {};
  gemm_core(xb, Bt, As, Bs, m0, n0, acc);
  const int t = threadIdx.x, lane = t & 63, wv = t >> 6;
  const int lm = lane & 15, quad = lane >> 4;
  const int wr = wv >> 1, wc = wv & 1;
  if (z < 2) {
    u16* tgt = (z == 0) ? Qg : Kg;
    const float sc = (z == 0) ? SMSCALE : 1.0f;   // fold softmax scale into Q
    #pragma unroll
    for (int i = 0; i < 4; ++i)
      #pragma unroll
      for (int j = 0; j < 4; ++j) {
        const int col = n0 + wc * 64 + j * 16 + lm;
        const int h = col >> 6, d = col & 63;
        #pragma unroll
        for (int reg = 0; reg < 4; ++reg) {
          const int row = m0 + wr * 64 + i * 16 + quad * 4 + reg;
          const int bb = row >> 11, nn = row & 2047;
          tgt[(((size_t)bb * 16 + h) * 2048 + nn) * 64 + d] = f2bf(acc[i][j][reg] * sc);
        }
      }
  } else {
    // V: transpose tile through LDS, two 64-col passes -> Vtg [bh][d][n]
    const int bb = m0 >> 11, nn0 = m0 & 2047;
    const int h0 = n0 >> 6;
    #pragma unroll
    for (int p = 0; p < 2; ++p) {
      if (wc == p) {
        #pragma unroll
        for (int i = 0; i < 4; ++i)
          #pragma unroll
          for (int j = 0; j < 4; ++j) {
            const int rT = j * 16 + lm;                         // d within pass (0..63)
            #pragma unroll
            for (int reg = 0; reg < 4; ++reg) {
              const int cT = wr * 64 + i * 16 + quad * 4 + reg; // token local (0..127)
              T[rT * 136 + cT] = f2bf(acc[i][j][reg]);
            }
          }
      }
      __syncthreads();
      #pragma unroll
      for (int cc = 0; cc < 4; ++cc) {
        int chunk = cc * 256 + t;
        int r = chunk >> 4, tk = (chunk & 15) * 8;
        frag8 v = *(const frag8*)(T + r * 136 + tk);
        *(frag8*)(Vtg + (((size_t)bb * 16 + h0 + p) * 64 + r) * 2048 + nn0 + tk) = v;
      }
      __syncthreads();
    }
  }
}

// ---------------- flash attention (causal), sequential paired q-tiles, diet softmax ----------------
// Register discipline (R3/R4 lesson): ONE accumulator set. Dual-acc joint-pair
// spilled to scratch (894 MB writes at (256,5), 260 MB at (256,4)). Sequential
// phases keep the R2-proven 48-VGPR profile; XCD swizzle recovers the L2 reuse.
__device__ __forceinline__ void attn_tile(const u16* Ks, const u16* Vts, u16* PsW,
                                          const frag8 aq[2], f32x4 o[4], float& l_run,
                                          int lm, int quad, int wv, bool diag) {
  f32x4 s[4];
  #pragma unroll
  for (int kt = 0; kt < 4; ++kt) {
    f32x4 z = {0.f, 0.f, 0.f, 0.f};
    #pragma unroll
    for (int dd = 0; dd < 2; ++dd) {
      frag8 ak = *(const frag8*)(Ks + (kt * 16 + lm) * 64 + (((dd * 4 + quad) ^ (lm & 7)) * 8));
      z = MFMA_BF16(ak, aq[dd], z);
    }
    s[kt] = z;
  }
  if (diag) {  // diagonal tile mask (wave-uniform branch); key>q -> -inf
    #pragma unroll
    for (int kt = 0; kt < 4; ++kt)
      #pragma unroll
      for (int rg = 0; rg < 4; ++rg)
        if (kt * 16 + quad * 4 + rg > wv * 16 + lm) s[kt][rg] = -3.0e38f;
  }
  float rs = 0.f;
  #pragma unroll
  for (int kt = 0; kt < 4; ++kt) {
    float p0 = exp2f(s[kt][0]);   // Q was pre-scaled by 1/sqrt(d)*log2(e)
    float p1 = exp2f(s[kt][1]);
    float p2 = exp2f(s[kt][2]);
    float p3 = exp2f(s[kt][3]);
    rs += (p0 + p1) + (p2 + p3);
    *(uint32_t*)(PsW + lm * 72 + kt * 16 + quad * 4)     = pack_bf16(p0, p1);
    *(uint32_t*)(PsW + lm * 72 + kt * 16 + quad * 4 + 2) = pack_bf16(p2, p3);
  }
  l_run += rs;   // cross-quad reduction deferred to epilogue
  #pragma unroll
  for (int ks = 0; ks < 2; ++ks) {
    frag8 bp = *(const frag8*)(PsW + lm * 72 + ks * 32 + quad * 8);
    #pragma unroll
    for (int dt = 0; dt < 4; ++dt) {
      frag8 av = *(const frag8*)(Vts + (dt * 16 + lm) * 64 + (((ks * 4 + quad) ^ (lm & 7)) * 8));
      o[dt] = MFMA_BF16(av, bp, o[dt]);
    }
  }
}

__global__ __launch_bounds__(256, 5) void k_attn(const u16* __restrict__ Qg,
                                                 const u16* __restrict__ Kg,
                                                 const u16* __restrict__ Vtg,
                                                 u16* __restrict__ ctx) {
  __shared__ __attribute__((aligned(16))) u16 Ks[64 * 64];    // swizzled
  __shared__ __attribute__((aligned(16))) u16 Vts[64 * 64];   // [d][key], swizzled
  __shared__ __attribute__((aligned(16))) u16 Ps[4 * 16 * 72];
  // swizzled grid: bid = pair*64 + bh_hi*8 + bh_lo -> bid%8 == bh%8 (XCD-stable per bh)
  const int bid = blockIdx.x;
  const int pair = bid >> 6;
  const int bh = ((bid >> 3) & 7) * 8 + (bid & 7);
  const int t = threadIdx.x, lane = t & 63, wv = t >> 6;
  const int lm = lane & 15, quad = lane >> 4;
  const int b = bh >> 4, h = bh & 15;
  u16* const PsW = Ps + wv * (16 * 72);

  #pragma unroll
  for (int phase = 0; phase < 2; ++phase) {
    const int qt = phase ? (31 - pair) : pair;

    frag8 aq[2];
    {
      const u16* qp = Qg + ((size_t)bh * 2048 + qt * 64 + wv * 16 + lm) * 64 + quad * 8;
      aq[0] = *(const frag8*)(qp);
      aq[1] = *(const frag8*)(qp + 32);
    }
    float l = 0.f;
    f32x4 o[4] = {};

    for (int kt0 = 0; kt0 <= qt; ++kt0) {
      #pragma unroll
      for (int it = 0; it < 2; ++it) {
        int chunk = it * 256 + t;
        int r = chunk >> 3, c = chunk & 7;
        int sc = (c ^ (r & 7)) * 8;
        async16(Kg  + ((size_t)bh * 2048 + kt0 * 64 + r) * 64 + sc, Ks  + (size_t)(it * 256 + wv * 64) * 8);
        async16(Vtg + ((size_t)bh * 64 + r) * 2048 + kt0 * 64 + sc, Vts + (size_t)(it * 256 + wv * 64) * 8);
      }
      __syncthreads();
      attn_tile(Ks, Vts, PsW, aq, o, l, lm, quad, wv, kt0 == qt);
      __syncthreads();
    }

    // epilogue: reduce l across quads, normalize, transpose O^T->[q][d] via PsW, 16B stores
    l += __shfl_xor(l, 16);
    l += __shfl_xor(l, 32);
    const float inv = 1.0f / l;
    #pragma unroll
    for (int dt = 0; dt < 4; ++dt) {
      *(uint32_t*)(PsW + lm * 72 + dt * 16 + quad * 4)     = pack_bf16(o[dt][0] * inv, o[dt][1] * inv);
      *(uint32_t*)(PsW + lm * 72 + dt * 16 + quad * 4 + 2) = pack_bf16(o[dt][2] * inv, o[dt][3] * inv);
    }
    const int rr = lane >> 2, cc = (lane & 3) * 8;
    const size_t row = (size_t)b * 2048 + qt * 64 + wv * 16 + rr;
    #pragma unroll
    for (int half = 0; half < 2; ++half) {
      frag8 vo = *(const frag8*)(PsW + rr * 72 + cc + half * 32);
      *(frag8*)(ctx + row * 1024 + h * 64 + cc + half * 32) = vo;
    }
  }
}

// ---------------- output projection GEMM (+bias, fp32 out) ----------------
__global__ __launch_bounds__(256) void k_gemm_out(const u16* __restrict__ ctx,
    const u16* __restrict__ Wot, const float* __restrict__ bo, float* __restrict__ out) {
  __shared__ __attribute__((aligned(16))) u16 As[128 * 32];
  __shared__ __attribute__((aligned(16))) u16 Bs[128 * 32];
  const int m0 = blockIdx.x * 128, n0 = blockIdx.y * 128;
  f32x4 acc[4][4] = {};
  gemm_core(ctx, Wot, As, Bs, m0, n0, acc);
  const int t = threadIdx.x, lane = t & 63, wv = t >> 6;
  const int lm = lane & 15, quad = lane >> 4;
  const int wr = wv >> 1, wc = wv & 1;
  #pragma unroll
  for (int i = 0; i < 4; ++i)
    #pragma unroll
    for (int j = 0; j < 4; ++j) {
      const int col = n0 + wc * 64 + j * 16 + lm;
      const float bias = bo[col];
      #pragma unroll
      for (int reg = 0; reg < 4; ++reg) {
        const int row = m0 + wr * 64 + i * 16 + quad * 4 + reg;
        out[(size_t)row * 1024 + col] = acc[i][j][reg] + bias;
      }
    }
}

extern "C" void kernel_launch(void* const* d_in, const int* in_sizes, int n_in,
                              void* d_out, int out_size, void* d_ws, size_t ws_size,
                              hipStream_t stream) {
  const float* x  = (const float*)d_in[0];
  const float* Wq = (const float*)d_in[1];
  const float* Wk = (const float*)d_in[2];
  const float* Wv = (const float*)d_in[3];
  const float* Wo = (const float*)d_in[4];
  const float* bo = (const float*)d_in[5];
  float* out = (float*)d_out;
  char* ws = (char*)d_ws;

  u16* xb   = (u16*)(ws);                          // 16 MB
  u16* Wqt  = (u16*)(ws + ((size_t)16 << 20));     //  2 MB each
  u16* Wkt  = (u16*)(ws + ((size_t)18 << 20));
  u16* Wvt  = (u16*)(ws + ((size_t)20 << 20));
  u16* Wot  = (u16*)(ws + ((size_t)22 << 20));
  u16* Qg   = (u16*)(ws + ((size_t)24 << 20));     // 16 MB [b,h,n,64] (pre-scaled)
  u16* Kg   = (u16*)(ws + ((size_t)40 << 20));     // 16 MB [b,h,n,64]
  u16* Vtg  = (u16*)(ws + ((size_t)56 << 20));     // 16 MB [b,h,64,n]
  u16* ctxb = (u16*)(ws + ((size_t)72 << 20));     // 16 MB

  k_convert_x<<<8192, 256, 0, stream>>>((const float4*)x, xb);
  k_transpose_w4<<<dim3(16, 16, 4), 256, 0, stream>>>(Wq, Wk, Wv, Wo, Wqt, Wkt, Wvt, Wot);
  k_gemm_qkv<<<dim3(64, 8, 3), 256, 0, stream>>>(xb, Wqt, Wkt, Wvt, Qg, Kg, Vtg);
  k_attn<<<1024, 256, 0, stream>>>(Qg, Kg, Vtg, ctxb);
  k_gemm_out<<<dim3(64, 8), 256, 0, stream>>>(ctxb, Wot, bo, out);
}

// Round 6
// 238.146 us; speedup vs baseline: 2.4041x; 1.2901x over previous
//
#include <hip/hip_runtime.h>
#include <stdint.h>

typedef unsigned short u16;
typedef __attribute__((ext_vector_type(8))) short frag8;   // 8 bf16 in 4 VGPRs
typedef __attribute__((ext_vector_type(4))) float f32x4;
typedef __attribute__((ext_vector_type(4))) unsigned short u16x4;

#define MFMA_BF16(a,b,c) __builtin_amdgcn_mfma_f32_16x16x32_bf16((a),(b),(c),0,0,0)
#define SMSCALE 0.18033688011112042f  /* (1/sqrt(64)) * log2(e) */

__device__ __forceinline__ u16 f2bf(float f) {
  union { float f; uint32_t u; } c; c.f = f;
  uint32_t u = c.u;
  uint32_t r = (u + 0x7fffu + ((u >> 16) & 1u)) >> 16;
  return (u16)r;
}

// pack two floats' bf16 (round-half-up) into one u32: low=a, high=b
__device__ __forceinline__ uint32_t pack_bf16(float a, float b) {
  uint32_t au = __float_as_uint(a) + 0x8000u;
  uint32_t bu = __float_as_uint(b) + 0x8000u;
  return __builtin_amdgcn_perm(bu, au, 0x07060302u);
}

__device__ __forceinline__ void async16(const void* g, void* l) {
  __builtin_amdgcn_global_load_lds((const __attribute__((address_space(1))) void*)g,
                                   (__attribute__((address_space(3))) void*)l,
                                   16, 0, 0);
}

// ---------------- convert x (fp32 -> bf16) ----------------
__global__ __launch_bounds__(256) void k_convert_x(const float4* __restrict__ x,
                                                   u16* __restrict__ xb) {
  int i = blockIdx.x * 256 + threadIdx.x;
  float4 v = x[i];
  u16x4 o;
  o.x = f2bf(v.x); o.y = f2bf(v.y); o.z = f2bf(v.z); o.w = f2bf(v.w);
  *(u16x4*)(xb + (size_t)i * 4) = o;
}

// ---------------- transpose all 4 W (fp32 [k][n] -> bf16 [n][k]) ----------------
__global__ __launch_bounds__(256) void k_transpose_w4(
    const float* __restrict__ W0, const float* __restrict__ W1,
    const float* __restrict__ W2, const float* __restrict__ W3,
    u16* __restrict__ D0, u16* __restrict__ D1,
    u16* __restrict__ D2, u16* __restrict__ D3) {
  __shared__ float tile[64][65];
  const int z = blockIdx.z;
  const float* src = (z == 0) ? W0 : (z == 1) ? W1 : (z == 2) ? W2 : W3;
  u16* dst = (z == 0) ? D0 : (z == 1) ? D1 : (z == 2) ? D2 : D3;
  const int bx = blockIdx.x * 64;  // k base
  const int by = blockIdx.y * 64;  // n base
  const int t = threadIdx.x;
  const int tc = (t & 15) * 4;
  const int tr = t >> 4;
  #pragma unroll
  for (int p = 0; p < 4; ++p) {
    int r = tr + p * 16;
    float4 v = *(const float4*)(src + (size_t)(bx + r) * 1024 + by + tc);
    tile[r][tc + 0] = v.x; tile[r][tc + 1] = v.y;
    tile[r][tc + 2] = v.z; tile[r][tc + 3] = v.w;
  }
  __syncthreads();
  #pragma unroll
  for (int p = 0; p < 4; ++p) {
    int r = tr + p * 16;
    u16x4 o;
    o.x = f2bf(tile[tc + 0][r]);
    o.y = f2bf(tile[tc + 1][r]);
    o.z = f2bf(tile[tc + 2][r]);
    o.w = f2bf(tile[tc + 3][r]);
    *(u16x4*)(dst + (size_t)(by + r) * 1024 + bx + tc) = o;
  }
}

// ---------------- fused QKV GEMM: 128x128 tile x 3 outputs, BK=64, swizzled LDS ----------------
// 96 MFMA per wave per barrier (vs 16 in the BK=32 single-output core) attacks the
// barrier-drain plateau; A-tile staged once for all three outputs. Grid 512 blocks
// = 2 blocks/CU (grid-limited), so 64 KB LDS + (256,2) 256-VGPR budget cost nothing.
__global__ __launch_bounds__(256, 2) void k_gemm_qkv(const u16* __restrict__ xb,
    const u16* __restrict__ Wqt, const u16* __restrict__ Wkt, const u16* __restrict__ Wvt,
    u16* __restrict__ Qg, u16* __restrict__ Kg, u16* __restrict__ Vtg) {
  __shared__ __attribute__((aligned(16))) u16 smem[4 * 128 * 64];  // A + 3xB, 64 KB
  u16* T = smem;                       // 64x136 u16 transpose buffer, reused post-loop
  const int m0 = blockIdx.x * 128, n0 = blockIdx.y * 128;
  const int t = threadIdx.x, lane = t & 63, wv = t >> 6;
  const int lm = lane & 15, quad = lane >> 4;
  const int wr = wv >> 1, wc = wv & 1;
  f32x4 acc[3][4][4] = {};

  for (int k0 = 0; k0 < 1024; k0 += 64) {
    // stage A (4 issues) + 3 B tiles (12 issues); source-column xor swizzle
    #pragma unroll
    for (int it = 0; it < 4; ++it) {
      int chunk = it * 256 + t;                    // 0..1023 16B chunks
      int r = chunk >> 3;
      int sc = ((chunk & 7) ^ (r & 7)) * 8;
      async16(xb + (size_t)(m0 + r) * 1024 + k0 + sc,
              smem + (size_t)(it * 256 + wv * 64) * 8);
    }
    #pragma unroll
    for (int z = 0; z < 3; ++z) {
      const u16* Bt = (z == 0) ? Wqt : (z == 1) ? Wkt : Wvt;
      #pragma unroll
      for (int it = 0; it < 4; ++it) {
        int chunk = it * 256 + t;
        int r = chunk >> 3;
        int sc = ((chunk & 7) ^ (r & 7)) * 8;
        async16(Bt + (size_t)(n0 + r) * 1024 + k0 + sc,
                smem + (size_t)((z + 1) * 1024 + it * 256 + wv * 64) * 8);
      }
    }
    __syncthreads();
    #pragma unroll
    for (int kk = 0; kk < 2; ++kk) {
      frag8 a[4];
      #pragma unroll
      for (int i = 0; i < 4; ++i) {
        int row = wr * 64 + i * 16 + lm;
        a[i] = *(const frag8*)(smem + row * 64 + (((kk * 4 + quad) ^ (row & 7)) * 8));
      }
      #pragma unroll
      for (int z = 0; z < 3; ++z) {
        #pragma unroll
        for (int j = 0; j < 4; ++j) {
          int row = wc * 64 + j * 16 + lm;
          frag8 b = *(const frag8*)(smem + (z + 1) * 8192 + row * 64 +
                                    (((kk * 4 + quad) ^ (row & 7)) * 8));
          #pragma unroll
          for (int i = 0; i < 4; ++i)
            acc[z][i][j] = MFMA_BF16(a[i], b, acc[z][i][j]);
        }
      }
    }
    __syncthreads();
  }

  // epilogue: Q (pre-scaled) and K scatter to [b,h,n,64]
  #pragma unroll
  for (int z = 0; z < 2; ++z) {
    u16* tgt = z ? Kg : Qg;
    const float sc = z ? 1.0f : SMSCALE;
    #pragma unroll
    for (int i = 0; i < 4; ++i)
      #pragma unroll
      for (int j = 0; j < 4; ++j) {
        const int col = n0 + wc * 64 + j * 16 + lm;
        const int h = col >> 6, d = col & 63;
        #pragma unroll
        for (int reg = 0; reg < 4; ++reg) {
          const int row = m0 + wr * 64 + i * 16 + quad * 4 + reg;
          const int bb = row >> 11, nn = row & 2047;
          tgt[(((size_t)bb * 16 + h) * 2048 + nn) * 64 + d] = f2bf(acc[z][i][j][reg] * sc);
        }
      }
  }
  // epilogue: V transposed through LDS -> Vtg [bh][d][n], two 64-col passes
  {
    const int bb = m0 >> 11, nn0 = m0 & 2047;
    const int h0 = n0 >> 6;
    #pragma unroll
    for (int p = 0; p < 2; ++p) {
      if (wc == p) {
        #pragma unroll
        for (int i = 0; i < 4; ++i)
          #pragma unroll
          for (int j = 0; j < 4; ++j) {
            const int rT = j * 16 + lm;                         // d within pass (0..63)
            #pragma unroll
            for (int reg = 0; reg < 4; ++reg) {
              const int cT = wr * 64 + i * 16 + quad * 4 + reg; // token local (0..127)
              T[rT * 136 + cT] = f2bf(acc[2][i][j][reg]);
            }
          }
      }
      __syncthreads();
      #pragma unroll
      for (int cc = 0; cc < 4; ++cc) {
        int chunk = cc * 256 + t;
        int r = chunk >> 4, tk = (chunk & 15) * 8;
        frag8 v = *(const frag8*)(T + r * 136 + tk);
        *(frag8*)(Vtg + (((size_t)bb * 16 + h0 + p) * 64 + r) * 2048 + nn0 + tk) = v;
      }
      __syncthreads();
    }
  }
}

// ---------------- flash attention (causal), sequential paired q-tiles, diet softmax ----------------
// Register discipline (R3/R4 lesson): ONE accumulator set. Dual-acc joint-pair
// spilled to scratch (894 MB writes at (256,5), 260 MB at (256,4)). Sequential
// phases keep the R2-proven 48-VGPR profile; XCD swizzle recovers the L2 reuse.
__device__ __forceinline__ void attn_tile(const u16* Ks, const u16* Vts, u16* PsW,
                                          const frag8 aq[2], f32x4 o[4], float& l_run,
                                          int lm, int quad, int wv, bool diag) {
  f32x4 s[4];
  #pragma unroll
  for (int kt = 0; kt < 4; ++kt) {
    f32x4 z = {0.f, 0.f, 0.f, 0.f};
    #pragma unroll
    for (int dd = 0; dd < 2; ++dd) {
      frag8 ak = *(const frag8*)(Ks + (kt * 16 + lm) * 64 + (((dd * 4 + quad) ^ (lm & 7)) * 8));
      z = MFMA_BF16(ak, aq[dd], z);
    }
    s[kt] = z;
  }
  if (diag) {  // diagonal tile mask (wave-uniform branch); key>q -> -inf
    #pragma unroll
    for (int kt = 0; kt < 4; ++kt)
      #pragma unroll
      for (int rg = 0; rg < 4; ++rg)
        if (kt * 16 + quad * 4 + rg > wv * 16 + lm) s[kt][rg] = -3.0e38f;
  }
  float rs = 0.f;
  #pragma unroll
  for (int kt = 0; kt < 4; ++kt) {
    float p0 = exp2f(s[kt][0]);   // Q was pre-scaled by 1/sqrt(d)*log2(e)
    float p1 = exp2f(s[kt][1]);
    float p2 = exp2f(s[kt][2]);
    float p3 = exp2f(s[kt][3]);
    rs += (p0 + p1) + (p2 + p3);
    *(uint32_t*)(PsW + lm * 72 + kt * 16 + quad * 4)     = pack_bf16(p0, p1);
    *(uint32_t*)(PsW + lm * 72 + kt * 16 + quad * 4 + 2) = pack_bf16(p2, p3);
  }
  l_run += rs;   // cross-quad reduction deferred to epilogue
  #pragma unroll
  for (int ks = 0; ks < 2; ++ks) {
    frag8 bp = *(const frag8*)(PsW + lm * 72 + ks * 32 + quad * 8);
    #pragma unroll
    for (int dt = 0; dt < 4; ++dt) {
      frag8 av = *(const frag8*)(Vts + (dt * 16 + lm) * 64 + (((ks * 4 + quad) ^ (lm & 7)) * 8));
      o[dt] = MFMA_BF16(av, bp, o[dt]);
    }
  }
}

__global__ __launch_bounds__(256, 5) void k_attn(const u16* __restrict__ Qg,
                                                 const u16* __restrict__ Kg,
                                                 const u16* __restrict__ Vtg,
                                                 u16* __restrict__ ctx) {
  __shared__ __attribute__((aligned(16))) u16 Ks[64 * 64];    // swizzled
  __shared__ __attribute__((aligned(16))) u16 Vts[64 * 64];   // [d][key], swizzled
  __shared__ __attribute__((aligned(16))) u16 Ps[4 * 16 * 72];
  // swizzled grid: bid = pair*64 + bh_hi*8 + bh_lo -> bid%8 == bh%8 (XCD-stable per bh)
  const int bid = blockIdx.x;
  const int pair = bid >> 6;
  const int bh = ((bid >> 3) & 7) * 8 + (bid & 7);
  const int t = threadIdx.x, lane = t & 63, wv = t >> 6;
  const int lm = lane & 15, quad = lane >> 4;
  const int b = bh >> 4, h = bh & 15;
  u16* const PsW = Ps + wv * (16 * 72);

  #pragma unroll
  for (int phase = 0; phase < 2; ++phase) {
    const int qt = phase ? (31 - pair) : pair;

    frag8 aq[2];
    {
      const u16* qp = Qg + ((size_t)bh * 2048 + qt * 64 + wv * 16 + lm) * 64 + quad * 8;
      aq[0] = *(const frag8*)(qp);
      aq[1] = *(const frag8*)(qp + 32);
    }
    float l = 0.f;
    f32x4 o[4] = {};

    for (int kt0 = 0; kt0 <= qt; ++kt0) {
      #pragma unroll
      for (int it = 0; it < 2; ++it) {
        int chunk = it * 256 + t;
        int r = chunk >> 3, c = chunk & 7;
        int sc = (c ^ (r & 7)) * 8;
        async16(Kg  + ((size_t)bh * 2048 + kt0 * 64 + r) * 64 + sc, Ks  + (size_t)(it * 256 + wv * 64) * 8);
        async16(Vtg + ((size_t)bh * 64 + r) * 2048 + kt0 * 64 + sc, Vts + (size_t)(it * 256 + wv * 64) * 8);
      }
      __syncthreads();
      attn_tile(Ks, Vts, PsW, aq, o, l, lm, quad, wv, kt0 == qt);
      __syncthreads();
    }

    // epilogue: reduce l across quads, normalize, transpose O^T->[q][d] via PsW, 16B stores
    l += __shfl_xor(l, 16);
    l += __shfl_xor(l, 32);
    const float inv = 1.0f / l;
    #pragma unroll
    for (int dt = 0; dt < 4; ++dt) {
      *(uint32_t*)(PsW + lm * 72 + dt * 16 + quad * 4)     = pack_bf16(o[dt][0] * inv, o[dt][1] * inv);
      *(uint32_t*)(PsW + lm * 72 + dt * 16 + quad * 4 + 2) = pack_bf16(o[dt][2] * inv, o[dt][3] * inv);
    }
    const int rr = lane >> 2, cc = (lane & 3) * 8;
    const size_t row = (size_t)b * 2048 + qt * 64 + wv * 16 + rr;
    #pragma unroll
    for (int half = 0; half < 2; ++half) {
      frag8 vo = *(const frag8*)(PsW + rr * 72 + cc + half * 32);
      *(frag8*)(ctx + row * 1024 + h * 64 + cc + half * 32) = vo;
    }
  }
}

// ---------------- output projection GEMM (+bias, fp32 out), BK=64, swizzled ----------------
__global__ __launch_bounds__(256) void k_gemm_out(const u16* __restrict__ ctx,
    const u16* __restrict__ Wot, const float* __restrict__ bo, float* __restrict__ out) {
  __shared__ __attribute__((aligned(16))) u16 As[128 * 64];
  __shared__ __attribute__((aligned(16))) u16 Bs[128 * 64];
  const int m0 = blockIdx.x * 128, n0 = blockIdx.y * 128;
  const int t = threadIdx.x, lane = t & 63, wv = t >> 6;
  const int lm = lane & 15, quad = lane >> 4;
  const int wr = wv >> 1, wc = wv & 1;
  f32x4 acc[4][4] = {};
  for (int k0 = 0; k0 < 1024; k0 += 64) {
    #pragma unroll
    for (int it = 0; it < 4; ++it) {
      int chunk = it * 256 + t;
      int r = chunk >> 3;
      int sc = ((chunk & 7) ^ (r & 7)) * 8;
      async16(ctx + (size_t)(m0 + r) * 1024 + k0 + sc, As + (size_t)(it * 256 + wv * 64) * 8);
      async16(Wot + (size_t)(n0 + r) * 1024 + k0 + sc, Bs + (size_t)(it * 256 + wv * 64) * 8);
    }
    __syncthreads();
    #pragma unroll
    for (int kk = 0; kk < 2; ++kk) {
      frag8 a[4];
      #pragma unroll
      for (int i = 0; i < 4; ++i) {
        int row = wr * 64 + i * 16 + lm;
        a[i] = *(const frag8*)(As + row * 64 + (((kk * 4 + quad) ^ (row & 7)) * 8));
      }
      #pragma unroll
      for (int j = 0; j < 4; ++j) {
        int row = wc * 64 + j * 16 + lm;
        frag8 b = *(const frag8*)(Bs + row * 64 + (((kk * 4 + quad) ^ (row & 7)) * 8));
        #pragma unroll
        for (int i = 0; i < 4; ++i)
          acc[i][j] = MFMA_BF16(a[i], b, acc[i][j]);
      }
    }
    __syncthreads();
  }
  #pragma unroll
  for (int i = 0; i < 4; ++i)
    #pragma unroll
    for (int j = 0; j < 4; ++j) {
      const int col = n0 + wc * 64 + j * 16 + lm;
      const float bias = bo[col];
      #pragma unroll
      for (int reg = 0; reg < 4; ++reg) {
        const int row = m0 + wr * 64 + i * 16 + quad * 4 + reg;
        out[(size_t)row * 1024 + col] = acc[i][j][reg] + bias;
      }
    }
}

extern "C" void kernel_launch(void* const* d_in, const int* in_sizes, int n_in,
                              void* d_out, int out_size, void* d_ws, size_t ws_size,
                              hipStream_t stream) {
  const float* x  = (const float*)d_in[0];
  const float* Wq = (const float*)d_in[1];
  const float* Wk = (const float*)d_in[2];
  const float* Wv = (const float*)d_in[3];
  const float* Wo = (const float*)d_in[4];
  const float* bo = (const float*)d_in[5];
  float* out = (float*)d_out;
  char* ws = (char*)d_ws;

  u16* xb   = (u16*)(ws);                          // 16 MB
  u16* Wqt  = (u16*)(ws + ((size_t)16 << 20));     //  2 MB each
  u16* Wkt  = (u16*)(ws + ((size_t)18 << 20));
  u16* Wvt  = (u16*)(ws + ((size_t)20 << 20));
  u16* Wot  = (u16*)(ws + ((size_t)22 << 20));
  u16* Qg   = (u16*)(ws + ((size_t)24 << 20));     // 16 MB [b,h,n,64] (pre-scaled)
  u16* Kg   = (u16*)(ws + ((size_t)40 << 20));     // 16 MB [b,h,n,64]
  u16* Vtg  = (u16*)(ws + ((size_t)56 << 20));     // 16 MB [b,h,64,n]
  u16* ctxb = (u16*)(ws + ((size_t)72 << 20));     // 16 MB

  k_convert_x<<<8192, 256, 0, stream>>>((const float4*)x, xb);
  k_transpose_w4<<<dim3(16, 16, 4), 256, 0, stream>>>(Wq, Wk, Wv, Wo, Wqt, Wkt, Wvt, Wot);
  k_gemm_qkv<<<dim3(64, 8), 256, 0, stream>>>(xb, Wqt, Wkt, Wvt, Qg, Kg, Vtg);
  k_attn<<<1024, 256, 0, stream>>>(Qg, Kg, Vtg, ctxb);
  k_gemm_out<<<dim3(64, 8), 256, 0, stream>>>(ctxb, Wot, bo, out);
}

// Round 7
// 232.932 us; speedup vs baseline: 2.4579x; 1.0224x over previous
//
#include <hip/hip_runtime.h>
#include <stdint.h>

typedef unsigned short u16;
typedef __attribute__((ext_vector_type(8))) short frag8;   // 8 bf16 in 4 VGPRs
typedef __attribute__((ext_vector_type(4))) float f32x4;
typedef __attribute__((ext_vector_type(4))) unsigned short u16x4;

#define MFMA_BF16(a,b,c) __builtin_amdgcn_mfma_f32_16x16x32_bf16((a),(b),(c),0,0,0)
#define SMSCALE 0.18033688011112042f  /* (1/sqrt(64)) * log2(e) */

__device__ __forceinline__ u16 f2bf(float f) {
  union { float f; uint32_t u; } c; c.f = f;
  uint32_t u = c.u;
  uint32_t r = (u + 0x7fffu + ((u >> 16) & 1u)) >> 16;
  return (u16)r;
}

// pack two floats' bf16 (round-half-up) into one u32: low=a, high=b
__device__ __forceinline__ uint32_t pack_bf16(float a, float b) {
  uint32_t au = __float_as_uint(a) + 0x8000u;
  uint32_t bu = __float_as_uint(b) + 0x8000u;
  return __builtin_amdgcn_perm(bu, au, 0x07060302u);
}

__device__ __forceinline__ void async16(const void* g, void* l) {
  __builtin_amdgcn_global_load_lds((const __attribute__((address_space(1))) void*)g,
                                   (__attribute__((address_space(3))) void*)l,
                                   16, 0, 0);
}

// ---------------- convert x (fp32 -> bf16) ----------------
__global__ __launch_bounds__(256) void k_convert_x(const float4* __restrict__ x,
                                                   u16* __restrict__ xb) {
  int i = blockIdx.x * 256 + threadIdx.x;
  float4 v = x[i];
  u16x4 o;
  o.x = f2bf(v.x); o.y = f2bf(v.y); o.z = f2bf(v.z); o.w = f2bf(v.w);
  *(u16x4*)(xb + (size_t)i * 4) = o;
}

// ---------------- transpose all 4 W (fp32 [k][n] -> bf16 [n][k]) ----------------
__global__ __launch_bounds__(256) void k_transpose_w4(
    const float* __restrict__ W0, const float* __restrict__ W1,
    const float* __restrict__ W2, const float* __restrict__ W3,
    u16* __restrict__ D0, u16* __restrict__ D1,
    u16* __restrict__ D2, u16* __restrict__ D3) {
  __shared__ float tile[64][65];
  const int z = blockIdx.z;
  const float* src = (z == 0) ? W0 : (z == 1) ? W1 : (z == 2) ? W2 : W3;
  u16* dst = (z == 0) ? D0 : (z == 1) ? D1 : (z == 2) ? D2 : D3;
  const int bx = blockIdx.x * 64;  // k base
  const int by = blockIdx.y * 64;  // n base
  const int t = threadIdx.x;
  const int tc = (t & 15) * 4;
  const int tr = t >> 4;
  #pragma unroll
  for (int p = 0; p < 4; ++p) {
    int r = tr + p * 16;
    float4 v = *(const float4*)(src + (size_t)(bx + r) * 1024 + by + tc);
    tile[r][tc + 0] = v.x; tile[r][tc + 1] = v.y;
    tile[r][tc + 2] = v.z; tile[r][tc + 3] = v.w;
  }
  __syncthreads();
  #pragma unroll
  for (int p = 0; p < 4; ++p) {
    int r = tr + p * 16;
    u16x4 o;
    o.x = f2bf(tile[tc + 0][r]);
    o.y = f2bf(tile[tc + 1][r]);
    o.z = f2bf(tile[tc + 2][r]);
    o.w = f2bf(tile[tc + 3][r]);
    *(u16x4*)(dst + (size_t)(by + r) * 1024 + bx + tc) = o;
  }
}

// ---------------- fused QKV GEMM: 128x128 tile x 3 outputs, BK=64, swizzled LDS ----------------
__global__ __launch_bounds__(256, 2) void k_gemm_qkv(const u16* __restrict__ xb,
    const u16* __restrict__ Wqt, const u16* __restrict__ Wkt, const u16* __restrict__ Wvt,
    u16* __restrict__ Qg, u16* __restrict__ Kg, u16* __restrict__ Vtg) {
  __shared__ __attribute__((aligned(16))) u16 smem[4 * 128 * 64];  // A + 3xB, 64 KB
  u16* T = smem;                       // 64x136 u16 transpose buffer, reused post-loop
  const int m0 = blockIdx.x * 128, n0 = blockIdx.y * 128;
  const int t = threadIdx.x, lane = t & 63, wv = t >> 6;
  const int lm = lane & 15, quad = lane >> 4;
  const int wr = wv >> 1, wc = wv & 1;
  f32x4 acc[3][4][4] = {};

  for (int k0 = 0; k0 < 1024; k0 += 64) {
    #pragma unroll
    for (int it = 0; it < 4; ++it) {
      int chunk = it * 256 + t;                    // 0..1023 16B chunks
      int r = chunk >> 3;
      int sc = ((chunk & 7) ^ (r & 7)) * 8;
      async16(xb + (size_t)(m0 + r) * 1024 + k0 + sc,
              smem + (size_t)(it * 256 + wv * 64) * 8);
    }
    #pragma unroll
    for (int z = 0; z < 3; ++z) {
      const u16* Bt = (z == 0) ? Wqt : (z == 1) ? Wkt : Wvt;
      #pragma unroll
      for (int it = 0; it < 4; ++it) {
        int chunk = it * 256 + t;
        int r = chunk >> 3;
        int sc = ((chunk & 7) ^ (r & 7)) * 8;
        async16(Bt + (size_t)(n0 + r) * 1024 + k0 + sc,
                smem + (size_t)((z + 1) * 1024 + it * 256 + wv * 64) * 8);
      }
    }
    __syncthreads();
    #pragma unroll
    for (int kk = 0; kk < 2; ++kk) {
      frag8 a[4];
      #pragma unroll
      for (int i = 0; i < 4; ++i) {
        int row = wr * 64 + i * 16 + lm;
        a[i] = *(const frag8*)(smem + row * 64 + (((kk * 4 + quad) ^ (row & 7)) * 8));
      }
      #pragma unroll
      for (int z = 0; z < 3; ++z) {
        #pragma unroll
        for (int j = 0; j < 4; ++j) {
          int row = wc * 64 + j * 16 + lm;
          frag8 b = *(const frag8*)(smem + (z + 1) * 8192 + row * 64 +
                                    (((kk * 4 + quad) ^ (row & 7)) * 8));
          #pragma unroll
          for (int i = 0; i < 4; ++i)
            acc[z][i][j] = MFMA_BF16(a[i], b, acc[z][i][j]);
        }
      }
    }
    __syncthreads();
  }

  // epilogue: Q (pre-scaled) and K scatter to [b,h,n,64]
  #pragma unroll
  for (int z = 0; z < 2; ++z) {
    u16* tgt = z ? Kg : Qg;
    const float sc = z ? 1.0f : SMSCALE;
    #pragma unroll
    for (int i = 0; i < 4; ++i)
      #pragma unroll
      for (int j = 0; j < 4; ++j) {
        const int col = n0 + wc * 64 + j * 16 + lm;
        const int h = col >> 6, d = col & 63;
        #pragma unroll
        for (int reg = 0; reg < 4; ++reg) {
          const int row = m0 + wr * 64 + i * 16 + quad * 4 + reg;
          const int bb = row >> 11, nn = row & 2047;
          tgt[(((size_t)bb * 16 + h) * 2048 + nn) * 64 + d] = f2bf(acc[z][i][j][reg] * sc);
        }
      }
  }
  // epilogue: V transposed through LDS -> Vtg [bh][d][n], two 64-col passes
  {
    const int bb = m0 >> 11, nn0 = m0 & 2047;
    const int h0 = n0 >> 6;
    #pragma unroll
    for (int p = 0; p < 2; ++p) {
      if (wc == p) {
        #pragma unroll
        for (int i = 0; i < 4; ++i)
          #pragma unroll
          for (int j = 0; j < 4; ++j) {
            const int rT = j * 16 + lm;                         // d within pass (0..63)
            #pragma unroll
            for (int reg = 0; reg < 4; ++reg) {
              const int cT = wr * 64 + i * 16 + quad * 4 + reg; // token local (0..127)
              T[rT * 136 + cT] = f2bf(acc[2][i][j][reg]);
            }
          }
      }
      __syncthreads();
      #pragma unroll
      for (int cc = 0; cc < 4; ++cc) {
        int chunk = cc * 256 + t;
        int r = chunk >> 4, tk = (chunk & 15) * 8;
        frag8 v = *(const frag8*)(T + r * 136 + tk);
        *(frag8*)(Vtg + (((size_t)bb * 16 + h0 + p) * 64 + r) * 2048 + nn0 + tk) = v;
      }
      __syncthreads();
    }
  }
}

// ---------------- flash attention (causal): 4 q-tiles per block, shared K/V frags ----------------
// R6 diagnosis: LDS-traffic-bound (each wave re-read full K+V tiles -> 1.28 KB/MFMA).
// Each block owns q-tiles {2i,2i+1,30-2i,31-2i} (66 tile-computes, perfectly balanced).
// K/V fragments are hoisted to registers ONCE per staged tile and reused by all active
// q-tiles (-> 0.5 KB/MFMA), K/V staged once for up to 4 q-tiles, double-buffered.
// Register budget ~200 -> (256,2). WRITE_SIZE is the spill tripwire (R3/R4 lesson).
__global__ __launch_bounds__(256, 2) void k_attn(const u16* __restrict__ Qg,
                                                 const u16* __restrict__ Kg,
                                                 const u16* __restrict__ Vtg,
                                                 u16* __restrict__ ctx) {
  __shared__ __attribute__((aligned(16))) u16 Ks[2][64 * 64];    // swizzled, dbuf
  __shared__ __attribute__((aligned(16))) u16 Vts[2][64 * 64];   // [d][key], swizzled, dbuf
  __shared__ __attribute__((aligned(16))) u16 Ps[4 * 16 * 72];
  // grid 512: bid = i*64 + bh_hi*8 + bh_lo -> bid%8 == bh%8 (XCD-stable per bh)
  const int bid = blockIdx.x;
  const int ib = bid >> 6;                       // 0..7
  const int bh = ((bid >> 3) & 7) * 8 + (bid & 7);
  const int qts[4] = {2 * ib, 2 * ib + 1, 30 - 2 * ib, 31 - 2 * ib};  // ascending
  const int t = threadIdx.x, lane = t & 63, wv = t >> 6;
  const int lm = lane & 15, quad = lane >> 4;
  const int b = bh >> 4, h = bh & 15;
  u16* const PsW = Ps + wv * (16 * 72);

  frag8 aq[4][2];
  #pragma unroll
  for (int qa = 0; qa < 4; ++qa) {
    const u16* qp = Qg + ((size_t)bh * 2048 + qts[qa] * 64 + wv * 16 + lm) * 64 + quad * 8;
    aq[qa][0] = *(const frag8*)(qp);
    aq[qa][1] = *(const frag8*)(qp + 32);
  }
  f32x4 o[4][4] = {};
  float l[4] = {0.f, 0.f, 0.f, 0.f};
  const int nst = 32 - 2 * ib;                   // staged tiles = qt_max+1

  auto stage = [&](int kt, int buf) {
    #pragma unroll
    for (int it = 0; it < 2; ++it) {
      int chunk = it * 256 + t;
      int r = chunk >> 3, c = chunk & 7;
      int sc = (c ^ (r & 7)) * 8;
      async16(Kg  + ((size_t)bh * 2048 + kt * 64 + r) * 64 + sc, &Ks[buf][(it * 256 + wv * 64) * 8]);
      async16(Vtg + ((size_t)bh * 64 + r) * 2048 + kt * 64 + sc,  &Vts[buf][(it * 256 + wv * 64) * 8]);
    }
  };

  stage(0, 0);
  for (int kt0 = 0; kt0 < nst; ++kt0) {
    const int cur = kt0 & 1;
    __syncthreads();                             // loads(cur) done; prior compute done
    if (kt0 + 1 < nst) stage(kt0 + 1, cur ^ 1);  // overlap next staging with compute

    // hoist K-frags once, reuse for all active q-tiles
    frag8 kf[8];
    #pragma unroll
    for (int kt = 0; kt < 4; ++kt)
      #pragma unroll
      for (int dd = 0; dd < 2; ++dd)
        kf[kt * 2 + dd] = *(const frag8*)(&Ks[cur][(kt * 16 + lm) * 64 + (((dd * 4 + quad) ^ (lm & 7)) * 8)]);

    uint32_t pk[4][8];
    #pragma unroll
    for (int qa = 0; qa < 4; ++qa) {
      if (qts[qa] < kt0) continue;               // wave-uniform
      f32x4 s[4];
      #pragma unroll
      for (int kt = 0; kt < 4; ++kt) {
        f32x4 z = {0.f, 0.f, 0.f, 0.f};
        z = MFMA_BF16(kf[kt * 2 + 0], aq[qa][0], z);
        z = MFMA_BF16(kf[kt * 2 + 1], aq[qa][1], z);
        s[kt] = z;
      }
      if (kt0 == qts[qa]) {                      // diagonal tile mask
        #pragma unroll
        for (int kt = 0; kt < 4; ++kt)
          #pragma unroll
          for (int rg = 0; rg < 4; ++rg)
            if (kt * 16 + quad * 4 + rg > wv * 16 + lm) s[kt][rg] = -3.0e38f;
      }
      float rs = 0.f;
      #pragma unroll
      for (int kt = 0; kt < 4; ++kt) {
        float p0 = exp2f(s[kt][0]);              // Q pre-scaled by 1/sqrt(d)*log2(e)
        float p1 = exp2f(s[kt][1]);
        float p2 = exp2f(s[kt][2]);
        float p3 = exp2f(s[kt][3]);
        rs += (p0 + p1) + (p2 + p3);
        pk[qa][kt * 2 + 0] = pack_bf16(p0, p1);
        pk[qa][kt * 2 + 1] = pack_bf16(p2, p3);
      }
      l[qa] += rs;
    }

    // hoist V-frags once, reuse for all active q-tiles
    frag8 vf[8];
    #pragma unroll
    for (int dt = 0; dt < 4; ++dt)
      #pragma unroll
      for (int ks = 0; ks < 2; ++ks)
        vf[dt * 2 + ks] = *(const frag8*)(&Vts[cur][(dt * 16 + lm) * 64 + (((ks * 4 + quad) ^ (lm & 7)) * 8)]);

    #pragma unroll
    for (int qa = 0; qa < 4; ++qa) {
      if (qts[qa] < kt0) continue;
      #pragma unroll
      for (int kt = 0; kt < 4; ++kt) {
        *(uint32_t*)(PsW + lm * 72 + kt * 16 + quad * 4)     = pk[qa][kt * 2 + 0];
        *(uint32_t*)(PsW + lm * 72 + kt * 16 + quad * 4 + 2) = pk[qa][kt * 2 + 1];
      }
      #pragma unroll
      for (int ks = 0; ks < 2; ++ks) {
        frag8 bp = *(const frag8*)(PsW + lm * 72 + ks * 32 + quad * 8);
        #pragma unroll
        for (int dt = 0; dt < 4; ++dt)
          o[qa][dt] = MFMA_BF16(vf[dt * 2 + ks], bp, o[qa][dt]);
      }
    }
  }

  // epilogues: reduce l across quads, normalize, transpose O^T->[q][d] via PsW, 16B stores
  #pragma unroll
  for (int qa = 0; qa < 4; ++qa) {
    float lv = l[qa];
    lv += __shfl_xor(lv, 16);
    lv += __shfl_xor(lv, 32);
    const float inv = 1.0f / lv;
    #pragma unroll
    for (int dt = 0; dt < 4; ++dt) {
      *(uint32_t*)(PsW + lm * 72 + dt * 16 + quad * 4)     = pack_bf16(o[qa][dt][0] * inv, o[qa][dt][1] * inv);
      *(uint32_t*)(PsW + lm * 72 + dt * 16 + quad * 4 + 2) = pack_bf16(o[qa][dt][2] * inv, o[qa][dt][3] * inv);
    }
    const int rr = lane >> 2, cc = (lane & 3) * 8;
    const size_t row = (size_t)b * 2048 + qts[qa] * 64 + wv * 16 + rr;
    #pragma unroll
    for (int half = 0; half < 2; ++half) {
      frag8 vo = *(const frag8*)(PsW + rr * 72 + cc + half * 32);
      *(frag8*)(ctx + row * 1024 + h * 64 + cc + half * 32) = vo;
    }
  }
}

// ---------------- output projection GEMM (+bias, fp32 out), BK=64, swizzled ----------------
__global__ __launch_bounds__(256) void k_gemm_out(const u16* __restrict__ ctx,
    const u16* __restrict__ Wot, const float* __restrict__ bo, float* __restrict__ out) {
  __shared__ __attribute__((aligned(16))) u16 As[128 * 64];
  __shared__ __attribute__((aligned(16))) u16 Bs[128 * 64];
  const int m0 = blockIdx.x * 128, n0 = blockIdx.y * 128;
  const int t = threadIdx.x, lane = t & 63, wv = t >> 6;
  const int lm = lane & 15, quad = lane >> 4;
  const int wr = wv >> 1, wc = wv & 1;
  f32x4 acc[4][4] = {};
  for (int k0 = 0; k0 < 1024; k0 += 64) {
    #pragma unroll
    for (int it = 0; it < 4; ++it) {
      int chunk = it * 256 + t;
      int r = chunk >> 3;
      int sc = ((chunk & 7) ^ (r & 7)) * 8;
      async16(ctx + (size_t)(m0 + r) * 1024 + k0 + sc, As + (size_t)(it * 256 + wv * 64) * 8);
      async16(Wot + (size_t)(n0 + r) * 1024 + k0 + sc, Bs + (size_t)(it * 256 + wv * 64) * 8);
    }
    __syncthreads();
    #pragma unroll
    for (int kk = 0; kk < 2; ++kk) {
      frag8 a[4];
      #pragma unroll
      for (int i = 0; i < 4; ++i) {
        int row = wr * 64 + i * 16 + lm;
        a[i] = *(const frag8*)(As + row * 64 + (((kk * 4 + quad) ^ (row & 7)) * 8));
      }
      #pragma unroll
      for (int j = 0; j < 4; ++j) {
        int row = wc * 64 + j * 16 + lm;
        frag8 b = *(const frag8*)(Bs + row * 64 + (((kk * 4 + quad) ^ (row & 7)) * 8));
        #pragma unroll
        for (int i = 0; i < 4; ++i)
          acc[i][j] = MFMA_BF16(a[i], b, acc[i][j]);
      }
    }
    __syncthreads();
  }
  #pragma unroll
  for (int i = 0; i < 4; ++i)
    #pragma unroll
    for (int j = 0; j < 4; ++j) {
      const int col = n0 + wc * 64 + j * 16 + lm;
      const float bias = bo[col];
      #pragma unroll
      for (int reg = 0; reg < 4; ++reg) {
        const int row = m0 + wr * 64 + i * 16 + quad * 4 + reg;
        out[(size_t)row * 1024 + col] = acc[i][j][reg] + bias;
      }
    }
}

extern "C" void kernel_launch(void* const* d_in, const int* in_sizes, int n_in,
                              void* d_out, int out_size, void* d_ws, size_t ws_size,
                              hipStream_t stream) {
  const float* x  = (const float*)d_in[0];
  const float* Wq = (const float*)d_in[1];
  const float* Wk = (const float*)d_in[2];
  const float* Wv = (const float*)d_in[3];
  const float* Wo = (const float*)d_in[4];
  const float* bo = (const float*)d_in[5];
  float* out = (float*)d_out;
  char* ws = (char*)d_ws;

  u16* xb   = (u16*)(ws);                          // 16 MB
  u16* Wqt  = (u16*)(ws + ((size_t)16 << 20));     //  2 MB each
  u16* Wkt  = (u16*)(ws + ((size_t)18 << 20));
  u16* Wvt  = (u16*)(ws + ((size_t)20 << 20));
  u16* Wot  = (u16*)(ws + ((size_t)22 << 20));
  u16* Qg   = (u16*)(ws + ((size_t)24 << 20));     // 16 MB [b,h,n,64] (pre-scaled)
  u16* Kg   = (u16*)(ws + ((size_t)40 << 20));     // 16 MB [b,h,n,64]
  u16* Vtg  = (u16*)(ws + ((size_t)56 << 20));     // 16 MB [b,h,64,n]
  u16* ctxb = (u16*)(ws + ((size_t)72 << 20));     // 16 MB

  k_convert_x<<<8192, 256, 0, stream>>>((const float4*)x, xb);
  k_transpose_w4<<<dim3(16, 16, 4), 256, 0, stream>>>(Wq, Wk, Wv, Wo, Wqt, Wkt, Wvt, Wot);
  k_gemm_qkv<<<dim3(64, 8), 256, 0, stream>>>(xb, Wqt, Wkt, Wvt, Qg, Kg, Vtg);
  k_attn<<<512, 256, 0, stream>>>(Qg, Kg, Vtg, ctxb);
  k_gemm_out<<<dim3(64, 8), 256, 0, stream>>>(ctxb, Wot, bo, out);
}

// Round 8
// 219.432 us; speedup vs baseline: 2.6091x; 1.0615x over previous
//
#include <hip/hip_runtime.h>
#include <stdint.h>

typedef unsigned short u16;
typedef __attribute__((ext_vector_type(8))) short frag8;   // 8 bf16 in 4 VGPRs
typedef __attribute__((ext_vector_type(4))) float f32x4;
typedef __attribute__((ext_vector_type(4))) unsigned short u16x4;
typedef __attribute__((ext_vector_type(2))) unsigned int u32x2;

#define MFMA_BF16(a,b,c) __builtin_amdgcn_mfma_f32_16x16x32_bf16((a),(b),(c),0,0,0)
#define SMSCALE 0.18033688011112042f  /* (1/sqrt(64)) * log2(e) */
#define EXP2R(x) __builtin_amdgcn_exp2f(x)   /* raw v_exp_f32, no ocml fixup */

__device__ __forceinline__ u16 f2bf(float f) {
  union { float f; uint32_t u; } c; c.f = f;
  uint32_t u = c.u;
  uint32_t r = (u + 0x7fffu + ((u >> 16) & 1u)) >> 16;
  return (u16)r;
}

// pack two floats' bf16 (round-half-up) into one u32: low=a, high=b
__device__ __forceinline__ uint32_t pack_bf16(float a, float b) {
  uint32_t au = __float_as_uint(a) + 0x8000u;
  uint32_t bu = __float_as_uint(b) + 0x8000u;
  return __builtin_amdgcn_perm(bu, au, 0x07060302u);
}
// truncating pack (1 instr): P in [0,1], proportional bias cancels in O=SumpV/Sump
__device__ __forceinline__ uint32_t pack_bf16_trunc(float a, float b) {
  return __builtin_amdgcn_perm(__float_as_uint(b), __float_as_uint(a), 0x07060302u);
}

__device__ __forceinline__ void async16(const void* g, void* l) {
  __builtin_amdgcn_global_load_lds((const __attribute__((address_space(1))) void*)g,
                                   (__attribute__((address_space(3))) void*)l,
                                   16, 0, 0);
}

// ---------------- convert x (fp32 -> bf16) ----------------
__global__ __launch_bounds__(256) void k_convert_x(const float4* __restrict__ x,
                                                   u16* __restrict__ xb) {
  int i = blockIdx.x * 256 + threadIdx.x;
  float4 v = x[i];
  u16x4 o;
  o.x = f2bf(v.x); o.y = f2bf(v.y); o.z = f2bf(v.z); o.w = f2bf(v.w);
  *(u16x4*)(xb + (size_t)i * 4) = o;
}

// ---------------- transpose all 4 W (fp32 [k][n] -> bf16 [n][k]) ----------------
__global__ __launch_bounds__(256) void k_transpose_w4(
    const float* __restrict__ W0, const float* __restrict__ W1,
    const float* __restrict__ W2, const float* __restrict__ W3,
    u16* __restrict__ D0, u16* __restrict__ D1,
    u16* __restrict__ D2, u16* __restrict__ D3) {
  __shared__ float tile[64][65];
  const int z = blockIdx.z;
  const float* src = (z == 0) ? W0 : (z == 1) ? W1 : (z == 2) ? W2 : W3;
  u16* dst = (z == 0) ? D0 : (z == 1) ? D1 : (z == 2) ? D2 : D3;
  const int bx = blockIdx.x * 64;  // k base
  const int by = blockIdx.y * 64;  // n base
  const int t = threadIdx.x;
  const int tc = (t & 15) * 4;
  const int tr = t >> 4;
  #pragma unroll
  for (int p = 0; p < 4; ++p) {
    int r = tr + p * 16;
    float4 v = *(const float4*)(src + (size_t)(bx + r) * 1024 + by + tc);
    tile[r][tc + 0] = v.x; tile[r][tc + 1] = v.y;
    tile[r][tc + 2] = v.z; tile[r][tc + 3] = v.w;
  }
  __syncthreads();
  #pragma unroll
  for (int p = 0; p < 4; ++p) {
    int r = tr + p * 16;
    u16x4 o;
    o.x = f2bf(tile[tc + 0][r]);
    o.y = f2bf(tile[tc + 1][r]);
    o.z = f2bf(tile[tc + 2][r]);
    o.w = f2bf(tile[tc + 3][r]);
    *(u16x4*)(dst + (size_t)(by + r) * 1024 + bx + tc) = o;
  }
}

// ---------------- fused QKV GEMM: 128x128 tile x 3 outputs, BK=64, swizzled LDS ----------------
__global__ __launch_bounds__(256, 2) void k_gemm_qkv(const u16* __restrict__ xb,
    const u16* __restrict__ Wqt, const u16* __restrict__ Wkt, const u16* __restrict__ Wvt,
    u16* __restrict__ Qg, u16* __restrict__ Kg, u16* __restrict__ Vtg) {
  __shared__ __attribute__((aligned(16))) u16 smem[4 * 128 * 64];  // A + 3xB, 64 KB
  u16* T = smem;                       // 64x136 u16 transpose buffer, reused post-loop
  const int m0 = blockIdx.x * 128, n0 = blockIdx.y * 128;
  const int t = threadIdx.x, lane = t & 63, wv = t >> 6;
  const int lm = lane & 15, quad = lane >> 4;
  const int wr = wv >> 1, wc = wv & 1;
  f32x4 acc[3][4][4] = {};

  for (int k0 = 0; k0 < 1024; k0 += 64) {
    #pragma unroll
    for (int it = 0; it < 4; ++it) {
      int chunk = it * 256 + t;                    // 0..1023 16B chunks
      int r = chunk >> 3;
      int sc = ((chunk & 7) ^ (r & 7)) * 8;
      async16(xb + (size_t)(m0 + r) * 1024 + k0 + sc,
              smem + (size_t)(it * 256 + wv * 64) * 8);
    }
    #pragma unroll
    for (int z = 0; z < 3; ++z) {
      const u16* Bt = (z == 0) ? Wqt : (z == 1) ? Wkt : Wvt;
      #pragma unroll
      for (int it = 0; it < 4; ++it) {
        int chunk = it * 256 + t;
        int r = chunk >> 3;
        int sc = ((chunk & 7) ^ (r & 7)) * 8;
        async16(Bt + (size_t)(n0 + r) * 1024 + k0 + sc,
                smem + (size_t)((z + 1) * 1024 + it * 256 + wv * 64) * 8);
      }
    }
    __syncthreads();
    #pragma unroll
    for (int kk = 0; kk < 2; ++kk) {
      frag8 a[4];
      #pragma unroll
      for (int i = 0; i < 4; ++i) {
        int row = wr * 64 + i * 16 + lm;
        a[i] = *(const frag8*)(smem + row * 64 + (((kk * 4 + quad) ^ (row & 7)) * 8));
      }
      #pragma unroll
      for (int z = 0; z < 3; ++z) {
        #pragma unroll
        for (int j = 0; j < 4; ++j) {
          int row = wc * 64 + j * 16 + lm;
          frag8 b = *(const frag8*)(smem + (z + 1) * 8192 + row * 64 +
                                    (((kk * 4 + quad) ^ (row & 7)) * 8));
          #pragma unroll
          for (int i = 0; i < 4; ++i)
            acc[z][i][j] = MFMA_BF16(a[i], b, acc[z][i][j]);
        }
      }
    }
    __syncthreads();
  }

  // epilogue: Q (pre-scaled) and K scatter to [b,h,n,64]
  #pragma unroll
  for (int z = 0; z < 2; ++z) {
    u16* tgt = z ? Kg : Qg;
    const float sc = z ? 1.0f : SMSCALE;
    #pragma unroll
    for (int i = 0; i < 4; ++i)
      #pragma unroll
      for (int j = 0; j < 4; ++j) {
        const int col = n0 + wc * 64 + j * 16 + lm;
        const int h = col >> 6, d = col & 63;
        #pragma unroll
        for (int reg = 0; reg < 4; ++reg) {
          const int row = m0 + wr * 64 + i * 16 + quad * 4 + reg;
          const int bb = row >> 11, nn = row & 2047;
          tgt[(((size_t)bb * 16 + h) * 2048 + nn) * 64 + d] = f2bf(acc[z][i][j][reg] * sc);
        }
      }
  }
  // epilogue: V transposed through LDS -> Vtg [bh][d][n], two 64-col passes
  {
    const int bb = m0 >> 11, nn0 = m0 & 2047;
    const int h0 = n0 >> 6;
    #pragma unroll
    for (int p = 0; p < 2; ++p) {
      if (wc == p) {
        #pragma unroll
        for (int i = 0; i < 4; ++i)
          #pragma unroll
          for (int j = 0; j < 4; ++j) {
            const int rT = j * 16 + lm;                         // d within pass (0..63)
            #pragma unroll
            for (int reg = 0; reg < 4; ++reg) {
              const int cT = wr * 64 + i * 16 + quad * 4 + reg; // token local (0..127)
              T[rT * 136 + cT] = f2bf(acc[2][i][j][reg]);
            }
          }
      }
      __syncthreads();
      #pragma unroll
      for (int cc = 0; cc < 4; ++cc) {
        int chunk = cc * 256 + t;
        int r = chunk >> 4, tk = (chunk & 15) * 8;
        frag8 v = *(const frag8*)(T + r * 136 + tk);
        *(frag8*)(Vtg + (((size_t)bb * 16 + h0 + p) * 64 + r) * 2048 + nn0 + tk) = v;
      }
      __syncthreads();
    }
  }
}

// ---------------- flash attention (causal): 4 q-tiles per block, VALU diet ----------------
// R7 diagnosis: VALU-bound (VALUBusy 50% vs MfmaUtil 17.5%); ocml exp2f fixup and
// 3-op bf16 packs were ~3x the intrinsic VALU cost. R8: raw v_exp_f32, 1-op trunc
// pack, b64 Ps writes, hoisted addressing. Register budget ~200 -> (256,2);
// WRITE_SIZE is the spill tripwire (R3/R4 lesson).
__global__ __launch_bounds__(256, 2) void k_attn(const u16* __restrict__ Qg,
                                                 const u16* __restrict__ Kg,
                                                 const u16* __restrict__ Vtg,
                                                 u16* __restrict__ ctx) {
  __shared__ __attribute__((aligned(16))) u16 Ks[2][64 * 64];    // swizzled, dbuf
  __shared__ __attribute__((aligned(16))) u16 Vts[2][64 * 64];   // [d][key], swizzled, dbuf
  __shared__ __attribute__((aligned(16))) u16 Ps[4 * 16 * 72];
  // grid 512: bid = i*64 + bh_hi*8 + bh_lo -> bid%8 == bh%8 (XCD-stable per bh)
  const int bid = blockIdx.x;
  const int ib = bid >> 6;                       // 0..7
  const int bh = ((bid >> 3) & 7) * 8 + (bid & 7);
  const int qts[4] = {2 * ib, 2 * ib + 1, 30 - 2 * ib, 31 - 2 * ib};  // ascending
  const int t = threadIdx.x, lane = t & 63, wv = t >> 6;
  const int lm = lane & 15, quad = lane >> 4;
  const int b = bh >> 4, h = bh & 15;
  u16* const PsW = Ps + wv * (16 * 72);

  frag8 aq[4][2];
  #pragma unroll
  for (int qa = 0; qa < 4; ++qa) {
    const u16* qp = Qg + ((size_t)bh * 2048 + qts[qa] * 64 + wv * 16 + lm) * 64 + quad * 8;
    aq[qa][0] = *(const frag8*)(qp);
    aq[qa][1] = *(const frag8*)(qp + 32);
  }
  f32x4 o[4][4] = {};
  float l[4] = {0.f, 0.f, 0.f, 0.f};
  const int nst = 32 - 2 * ib;                   // staged tiles = qt_max+1

  // hoisted staging source pointers (advance by constant per kt)
  const u16* ksrc[2]; const u16* vsrc[2];
  #pragma unroll
  for (int it = 0; it < 2; ++it) {
    int chunk = it * 256 + t;
    int r = chunk >> 3, c = chunk & 7;
    int sc = (c ^ (r & 7)) * 8;
    ksrc[it] = Kg  + ((size_t)bh * 2048 + r) * 64 + sc;   // += 4096 per kt
    vsrc[it] = Vtg + ((size_t)bh * 64 + r) * 2048 + sc;   // += 64 per kt
  }
  // hoisted LDS fragment offsets (identical pattern for K and V tiles)
  int offs[8];
  #pragma unroll
  for (int x = 0; x < 4; ++x)
    #pragma unroll
    for (int y = 0; y < 2; ++y)
      offs[x * 2 + y] = (x * 16 + lm) * 64 + (((y * 4 + quad) ^ (lm & 7)) * 8);

  auto stage = [&](int kt, int buf) {
    #pragma unroll
    for (int it = 0; it < 2; ++it) {
      async16(ksrc[it] + (size_t)kt * 4096, &Ks[buf][(it * 256 + wv * 64) * 8]);
      async16(vsrc[it] + (size_t)kt * 64,   &Vts[buf][(it * 256 + wv * 64) * 8]);
    }
  };

  stage(0, 0);
  for (int kt0 = 0; kt0 < nst; ++kt0) {
    const int cur = kt0 & 1;
    __syncthreads();                             // loads(cur) done; prior compute done
    if (kt0 + 1 < nst) stage(kt0 + 1, cur ^ 1);  // overlap next staging with compute

    // hoist K-frags once, reuse for all active q-tiles
    frag8 kf[8];
    #pragma unroll
    for (int i = 0; i < 8; ++i) kf[i] = *(const frag8*)(&Ks[cur][offs[i]]);

    uint32_t pk[4][8];
    #pragma unroll
    for (int qa = 0; qa < 4; ++qa) {
      if (qts[qa] < kt0) continue;               // wave-uniform
      f32x4 s[4];
      #pragma unroll
      for (int kt = 0; kt < 4; ++kt) {
        f32x4 z = {0.f, 0.f, 0.f, 0.f};
        z = MFMA_BF16(kf[kt * 2 + 0], aq[qa][0], z);
        z = MFMA_BF16(kf[kt * 2 + 1], aq[qa][1], z);
        s[kt] = z;
      }
      if (kt0 == qts[qa]) {                      // diagonal tile mask
        #pragma unroll
        for (int kt = 0; kt < 4; ++kt)
          #pragma unroll
          for (int rg = 0; rg < 4; ++rg)
            if (kt * 16 + quad * 4 + rg > wv * 16 + lm) s[kt][rg] = -3.0e38f;
      }
      float rs = 0.f;
      #pragma unroll
      for (int kt = 0; kt < 4; ++kt) {
        float p0 = EXP2R(s[kt][0]);              // Q pre-scaled by 1/sqrt(d)*log2(e)
        float p1 = EXP2R(s[kt][1]);
        float p2 = EXP2R(s[kt][2]);
        float p3 = EXP2R(s[kt][3]);
        rs += (p0 + p1) + (p2 + p3);
        pk[qa][kt * 2 + 0] = pack_bf16_trunc(p0, p1);
        pk[qa][kt * 2 + 1] = pack_bf16_trunc(p2, p3);
      }
      l[qa] += rs;
    }

    // hoist V-frags once, reuse for all active q-tiles
    frag8 vf[8];
    #pragma unroll
    for (int i = 0; i < 8; ++i) vf[i] = *(const frag8*)(&Vts[cur][offs[i]]);

    #pragma unroll
    for (int qa = 0; qa < 4; ++qa) {
      if (qts[qa] < kt0) continue;
      #pragma unroll
      for (int kt = 0; kt < 4; ++kt) {
        u32x2 w; w.x = pk[qa][kt * 2 + 0]; w.y = pk[qa][kt * 2 + 1];
        *(u32x2*)(PsW + lm * 72 + kt * 16 + quad * 4) = w;
      }
      #pragma unroll
      for (int ks = 0; ks < 2; ++ks) {
        frag8 bp = *(const frag8*)(PsW + lm * 72 + ks * 32 + quad * 8);
        #pragma unroll
        for (int dt = 0; dt < 4; ++dt)
          o[qa][dt] = MFMA_BF16(vf[dt * 2 + ks], bp, o[qa][dt]);
      }
    }
  }

  // epilogues: reduce l across quads, normalize, transpose O^T->[q][d] via PsW, 16B stores
  #pragma unroll
  for (int qa = 0; qa < 4; ++qa) {
    float lv = l[qa];
    lv += __shfl_xor(lv, 16);
    lv += __shfl_xor(lv, 32);
    const float inv = 1.0f / lv;
    #pragma unroll
    for (int dt = 0; dt < 4; ++dt) {
      *(uint32_t*)(PsW + lm * 72 + dt * 16 + quad * 4)     = pack_bf16(o[qa][dt][0] * inv, o[qa][dt][1] * inv);
      *(uint32_t*)(PsW + lm * 72 + dt * 16 + quad * 4 + 2) = pack_bf16(o[qa][dt][2] * inv, o[qa][dt][3] * inv);
    }
    const int rr = lane >> 2, cc = (lane & 3) * 8;
    const size_t row = (size_t)b * 2048 + qts[qa] * 64 + wv * 16 + rr;
    #pragma unroll
    for (int half = 0; half < 2; ++half) {
      frag8 vo = *(const frag8*)(PsW + rr * 72 + cc + half * 32);
      *(frag8*)(ctx + row * 1024 + h * 64 + cc + half * 32) = vo;
    }
  }
}

// ---------------- output projection GEMM (+bias, fp32 out), BK=64, swizzled ----------------
__global__ __launch_bounds__(256) void k_gemm_out(const u16* __restrict__ ctx,
    const u16* __restrict__ Wot, const float* __restrict__ bo, float* __restrict__ out) {
  __shared__ __attribute__((aligned(16))) u16 As[128 * 64];
  __shared__ __attribute__((aligned(16))) u16 Bs[128 * 64];
  const int m0 = blockIdx.x * 128, n0 = blockIdx.y * 128;
  const int t = threadIdx.x, lane = t & 63, wv = t >> 6;
  const int lm = lane & 15, quad = lane >> 4;
  const int wr = wv >> 1, wc = wv & 1;
  f32x4 acc[4][4] = {};
  for (int k0 = 0; k0 < 1024; k0 += 64) {
    #pragma unroll
    for (int it = 0; it < 4; ++it) {
      int chunk = it * 256 + t;
      int r = chunk >> 3;
      int sc = ((chunk & 7) ^ (r & 7)) * 8;
      async16(ctx + (size_t)(m0 + r) * 1024 + k0 + sc, As + (size_t)(it * 256 + wv * 64) * 8);
      async16(Wot + (size_t)(n0 + r) * 1024 + k0 + sc, Bs + (size_t)(it * 256 + wv * 64) * 8);
    }
    __syncthreads();
    #pragma unroll
    for (int kk = 0; kk < 2; ++kk) {
      frag8 a[4];
      #pragma unroll
      for (int i = 0; i < 4; ++i) {
        int row = wr * 64 + i * 16 + lm;
        a[i] = *(const frag8*)(As + row * 64 + (((kk * 4 + quad) ^ (row & 7)) * 8));
      }
      #pragma unroll
      for (int j = 0; j < 4; ++j) {
        int row = wc * 64 + j * 16 + lm;
        frag8 b = *(const frag8*)(Bs + row * 64 + (((kk * 4 + quad) ^ (row & 7)) * 8));
        #pragma unroll
        for (int i = 0; i < 4; ++i)
          acc[i][j] = MFMA_BF16(a[i], b, acc[i][j]);
      }
    }
    __syncthreads();
  }
  #pragma unroll
  for (int i = 0; i < 4; ++i)
    #pragma unroll
    for (int j = 0; j < 4; ++j) {
      const int col = n0 + wc * 64 + j * 16 + lm;
      const float bias = bo[col];
      #pragma unroll
      for (int reg = 0; reg < 4; ++reg) {
        const int row = m0 + wr * 64 + i * 16 + quad * 4 + reg;
        out[(size_t)row * 1024 + col] = acc[i][j][reg] + bias;
      }
    }
}

extern "C" void kernel_launch(void* const* d_in, const int* in_sizes, int n_in,
                              void* d_out, int out_size, void* d_ws, size_t ws_size,
                              hipStream_t stream) {
  const float* x  = (const float*)d_in[0];
  const float* Wq = (const float*)d_in[1];
  const float* Wk = (const float*)d_in[2];
  const float* Wv = (const float*)d_in[3];
  const float* Wo = (const float*)d_in[4];
  const float* bo = (const float*)d_in[5];
  float* out = (float*)d_out;
  char* ws = (char*)d_ws;

  u16* xb   = (u16*)(ws);                          // 16 MB
  u16* Wqt  = (u16*)(ws + ((size_t)16 << 20));     //  2 MB each
  u16* Wkt  = (u16*)(ws + ((size_t)18 << 20));
  u16* Wvt  = (u16*)(ws + ((size_t)20 << 20));
  u16* Wot  = (u16*)(ws + ((size_t)22 << 20));
  u16* Qg   = (u16*)(ws + ((size_t)24 << 20));     // 16 MB [b,h,n,64] (pre-scaled)
  u16* Kg   = (u16*)(ws + ((size_t)40 << 20));     // 16 MB [b,h,n,64]
  u16* Vtg  = (u16*)(ws + ((size_t)56 << 20));     // 16 MB [b,h,64,n]
  u16* ctxb = (u16*)(ws + ((size_t)72 << 20));     // 16 MB

  k_convert_x<<<8192, 256, 0, stream>>>((const float4*)x, xb);
  k_transpose_w4<<<dim3(16, 16, 4), 256, 0, stream>>>(Wq, Wk, Wv, Wo, Wqt, Wkt, Wvt, Wot);
  k_gemm_qkv<<<dim3(64, 8), 256, 0, stream>>>(xb, Wqt, Wkt, Wvt, Qg, Kg, Vtg);
  k_attn<<<512, 256, 0, stream>>>(Qg, Kg, Vtg, ctxb);
  k_gemm_out<<<dim3(64, 8), 256, 0, stream>>>(ctxb, Wot, bo, out);
}